// Round 10
// baseline (553.871 us; speedup 1.0000x reference)
//
#include <hip/hip_runtime.h>
#include <hip/hip_bf16.h>

// ---------------------------------------------------------------------------
// GAT x3 + fc + MLP. R20: depth-3 REGISTER rotation in both MFMA GEMMs.
// R17/R19 analysis: reg-staged depth-2 gives only ~1 iteration of load
// flight; loaded HBM latency ~2 iters -> every iteration stalls at WRITER's
// implicit vmcnt (iter ~2200cy, GEMMs capped at ~13 GB/s/CU, half of m13's
// 24.6). Fix: tile t lives in reg-set t%3 (statically named, rule #20);
// iter kt: WRITE set (kt+1)%3 -> LDS buf b^1, RELOAD freed set kt%3 with
// tile kt+3 => 2 iterations of flight. LDS stays 2x16KB double buffer.
// gat_agg = R17 form (fabric-roofline 50.3us, leave). CSR/conv unchanged.
// Baseline R19 = 510.8us.
// ---------------------------------------------------------------------------

#define GAT_SLOPE 0.2f
#define ACT_SLOPE 0.01f

typedef unsigned short ushort_t;
typedef __attribute__((ext_vector_type(8))) short bf16x8;
typedef __attribute__((ext_vector_type(8))) unsigned short ushort8v;
typedef __attribute__((ext_vector_type(4))) float floatx4;

__device__ __forceinline__ float lrelu(float x, float s) {
    return fmaxf(x, s * x);   // valid for 0<s<1
}

__device__ __forceinline__ ushort_t f2bf(float f) {
    union { float f; unsigned u; } x; x.f = f;
    unsigned r = x.u + 0x7FFF + ((x.u >> 16) & 1);   // round-nearest-even
    return (ushort_t)(r >> 16);
}

__device__ __forceinline__ float bf2f(ushort_t u) {
    union { unsigned u; float f; } x; x.u = ((unsigned)u) << 16;
    return x.f;
}

// ---------------- edge-index format probe ----------------
__global__ void detect_fmt(const int* __restrict__ raw, int nwords, int* flag) {
    __shared__ int nz;
    if (threadIdx.x == 0) nz = 0;
    __syncthreads();
    int lim = nwords < 4096 ? nwords : 4096;
    for (int i = threadIdx.x * 2 + 1; i < lim; i += 512)
        if (raw[i] != 0) atomicAdd(&nz, 1);
    __syncthreads();
    if (threadIdx.x == 0) *flag = (nz == 0) ? 1 : 0;   // 1 => int64 storage
}

__global__ void zero2(int* __restrict__ a, int* __restrict__ b, int n) {
    int i = blockIdx.x * blockDim.x + threadIdx.x;
    if (i < n) { a[i] = 0; b[i] = 0; }
}

__global__ void convert_count(const int* __restrict__ raw, int E,
                              const int* __restrict__ flag,
                              int* __restrict__ idx32, int* __restrict__ counts) {
    int i = blockIdx.x * blockDim.x + threadIdx.x;
    if (i >= E) return;
    int f = *flag;
    int s = f ? raw[2 * i] : raw[i];
    int d = f ? raw[2 * (E + i)] : raw[E + i];
    idx32[i] = s;
    idx32[E + i] = d;
    atomicAdd(&counts[d], 1);
}

__global__ void scan_block(const int* __restrict__ counts, int* __restrict__ inc,
                           int* __restrict__ blockSums, int N) {
    __shared__ int sh[256];
    int i = blockIdx.x * 256 + threadIdx.x;
    int v = (i < N) ? counts[i] : 0;
    sh[threadIdx.x] = v;
    __syncthreads();
    for (int off = 1; off < 256; off <<= 1) {
        int t = (threadIdx.x >= off) ? sh[threadIdx.x - off] : 0;
        __syncthreads();
        sh[threadIdx.x] += t;
        __syncthreads();
    }
    if (i < N) inc[i] = sh[threadIdx.x];
    if (threadIdx.x == 255) blockSums[blockIdx.x] = sh[255];
}

__global__ void scan_sums(int* __restrict__ blockSums, int nb, int* __restrict__ row_ptr) {
    __shared__ int sh[512];
    int v = ((int)threadIdx.x < nb) ? blockSums[threadIdx.x] : 0;
    sh[threadIdx.x] = v;
    __syncthreads();
    for (int off = 1; off < 512; off <<= 1) {
        int t = (threadIdx.x >= off) ? sh[threadIdx.x - off] : 0;
        __syncthreads();
        sh[threadIdx.x] += t;
        __syncthreads();
    }
    if ((int)threadIdx.x < nb) blockSums[threadIdx.x] = sh[threadIdx.x];
    if (threadIdx.x == 0) row_ptr[0] = 0;
}

__global__ void scan_add(const int* __restrict__ inc, const int* __restrict__ blockSums,
                         int* __restrict__ row_ptr, int N) {
    int i = blockIdx.x * 256 + threadIdx.x;
    if (i < N) row_ptr[i + 1] = inc[i] + (blockIdx.x > 0 ? blockSums[blockIdx.x - 1] : 0);
}

__global__ void edge_fill(const int* __restrict__ src, const int* __restrict__ dst, int E,
                          const int* __restrict__ row_ptr, int* __restrict__ cursor,
                          int* __restrict__ col) {
    int i = blockIdx.x * blockDim.x + threadIdx.x;
    if (i < E) {
        int d = dst[i];
        int pos = row_ptr[d] + atomicAdd(&cursor[d], 1);
        col[pos] = src[i];
    }
}

// ---------------- conversions ----------------
__global__ void convert_padrow(const float* __restrict__ in, ushort_t* __restrict__ out,
                               int M, int Kr, int Kp) {
    int i = blockIdx.x * blockDim.x + threadIdx.x;
    if (i >= M * Kp) return;
    int r = i / Kp, c = i - r * Kp;
    out[i] = f2bf((c < Kr) ? in[(size_t)r * Kr + c] : 0.f);
}

struct WConv { const float* in; ushort_t* out; int Kp, Kr, N, Npad, blkOff; };
struct WConvArr { WConv e[7]; int n; };

__global__ void convert_w_multi(WConvArr a) {
    int b = blockIdx.x;
    int ei = 0;
    for (int k = 1; k < a.n; k++)
        if (b >= a.e[k].blkOff) ei = k;
    WConv w = a.e[ei];
    int i = (b - w.blkOff) * 256 + threadIdx.x;
    if (i >= w.Npad * w.Kp) return;
    int n = i / w.Kp, k = i - n * w.Kp;
    float v = (n < w.N && k < w.Kr) ? w.in[(size_t)k * w.N + n] : 0.f;
    w.out[i] = f2bf(v);
}

// ---- shared staging macros for the depth-3 register rotation --------------
// set s holds tile t where t%3 == s. All names static (no scratch).
#define DECL_SETS()                                   \
    ushort8v A00, A01, B00, B01;                      \
    ushort8v A10, A11, B10, B11;                      \
    ushort8v A20, A21, B20, B21

#define LOADR_S(s, tt)                                \
    do {                                              \
        int k0_ = (tt) << 5;                          \
        A##s##0 = *(const ushort8v*)(gA0 + k0_);      \
        A##s##1 = *(const ushort8v*)(gA1 + k0_);      \
        B##s##0 = *(const ushort8v*)(gB0 + k0_);      \
        B##s##1 = *(const ushort8v*)(gB1 + k0_);      \
    } while (0)

#define WRITER_S(s, b)                                \
    do {                                              \
        *(ushort8v*)(&As[b][wsl0]) = A##s##0;         \
        *(ushort8v*)(&As[b][wsl1]) = A##s##1;         \
        *(ushort8v*)(&Bs[b][wsl0]) = B##s##0;         \
        *(ushort8v*)(&Bs[b][wsl1]) = B##s##1;         \
    } while (0)

// at iter kt: write set (kt+1)%3 (tile kt+1) to buf b^1, reload freed set
// kt%3 with tile kt+3  => tile kt+3 in flight for 2 full iterations.
#define PIPE_STEP(kt, b)                              \
    do {                                              \
        int nxt_ = (kt) + 1;                          \
        if (nxt_ < nt) {                              \
            int selw_ = nxt_ % 3;                     \
            int pre_ = (kt) + 3;                      \
            int sell_ = (kt) % 3;                     \
            if (selw_ == 0) WRITER_S(0, (b) ^ 1);     \
            else if (selw_ == 1) WRITER_S(1, (b) ^ 1);\
            else WRITER_S(2, (b) ^ 1);                \
            if (pre_ < nt) {                          \
                if (sell_ == 0) LOADR_S(0, pre_);     \
                else if (sell_ == 1) LOADR_S(1, pre_);\
                else LOADR_S(2, pre_);                \
            }                                         \
        }                                             \
    } while (0)

// ---------------- GAT GEMM: depth-3 reg rotation, 1 barrier/iter -----------
__global__ __launch_bounds__(256) void gemm_gat(
    const ushort_t* __restrict__ A, const ushort_t* __restrict__ Bt,
    const float* __restrict__ a_src, const float* __restrict__ a_dst,
    ushort_t* __restrict__ Hbf, float* __restrict__ al_s, float* __restrict__ al_d,
    int M, int K) {
    __shared__ __align__(16) ushort_t As[2][128 * 32];
    __shared__ __align__(16) ushort_t Bs[2][128 * 32];
    int t = threadIdx.x;
    int wave = t >> 6, lane = t & 63;
    int wm = (wave >> 1) << 6;
    int wn = (wave & 1) << 6;
    int rowBase = blockIdx.y << 7;
    int colBase = blockIdx.x << 7;
    int lrow = lane & 15, lquad = lane >> 4;
    floatx4 acc[4][4];
#pragma unroll
    for (int i = 0; i < 4; i++)
#pragma unroll
        for (int j = 0; j < 4; j++) acc[i][j] = (floatx4){0.f, 0.f, 0.f, 0.f};

    int c0 = wave * 64 + lane;
    const ushort_t* gA0 = A + (size_t)(rowBase + (c0 >> 2)) * K + ((c0 & 3) << 3);
    const ushort_t* gB0 = Bt + (size_t)(colBase + (c0 >> 2)) * K + ((c0 & 3) << 3);
    int c1 = 256 + c0;
    const ushort_t* gA1 = A + (size_t)(rowBase + (c1 >> 2)) * K + ((c1 & 3) << 3);
    const ushort_t* gB1 = Bt + (size_t)(colBase + (c1 >> 2)) * K + ((c1 & 3) << 3);
    const int wsl0 = (wave * 64 + lane) * 8;
    const int wsl1 = (256 + wave * 64 + lane) * 8;

    const int nt = K >> 5;   // K in {96,256} -> nt in {3,8}
    DECL_SETS();

    LOADR_S(0, 0);
    LOADR_S(1, 1);
    if (nt > 2) LOADR_S(2, 2);
    WRITER_S(0, 0);            // compiler waits only set-0's loads
    asm volatile("s_waitcnt lgkmcnt(0)" ::: "memory");
    __builtin_amdgcn_s_barrier();

    for (int kt = 0; kt < nt; ++kt) {
        int b = kt & 1;
        PIPE_STEP(kt, b);
        bf16x8 af[4], bfv[4];
#pragma unroll
        for (int i = 0; i < 4; i++)
            af[i] = *(const bf16x8*)(&As[b][(wm + i * 16 + lrow) * 32 + lquad * 8]);
#pragma unroll
        for (int j = 0; j < 4; j++)
            bfv[j] = *(const bf16x8*)(&Bs[b][(wn + j * 16 + lrow) * 32 + lquad * 8]);
#pragma unroll
        for (int i = 0; i < 4; i++)
#pragma unroll
            for (int j = 0; j < 4; j++)
                acc[i][j] = __builtin_amdgcn_mfma_f32_16x16x32_bf16(af[i], bfv[j],
                                                                    acc[i][j], 0, 0, 0);
        asm volatile("s_waitcnt lgkmcnt(0)" ::: "memory");
        __builtin_amdgcn_s_barrier();
    }

    // epilogue: al_s/al_d per (row, head) + bf16 h store (NCOL=256)
    int head = (colBase + wn) >> 6;
    float avs[4], avd[4];
#pragma unroll
    for (int j = 0; j < 4; j++) {
        avs[j] = a_src[head * 64 + j * 16 + lrow];
        avd[j] = a_dst[head * 64 + j * 16 + lrow];
    }
#pragma unroll
    for (int i = 0; i < 4; i++) {
#pragma unroll
        for (int r = 0; r < 4; r++) {
            float ps = 0.f, pd = 0.f;
#pragma unroll
            for (int j = 0; j < 4; j++) {
                ps += acc[i][j][r] * avs[j];
                pd += acc[i][j][r] * avd[j];
            }
#pragma unroll
            for (int off = 1; off < 16; off <<= 1) {
                ps += __shfl_xor(ps, off);
                pd += __shfl_xor(pd, off);
            }
            if (lrow == 0) {
                int gr = rowBase + wm + i * 16 + lquad * 4 + r;
                al_s[gr * 4 + head] = ps;
                al_d[gr * 4 + head] = pd;
            }
        }
        int grb = rowBase + wm + i * 16 + lquad * 4;
#pragma unroll
        for (int j = 0; j < 4; j++) {
            int gc = colBase + wn + j * 16 + lrow;
#pragma unroll
            for (int r = 0; r < 4; r++)
                Hbf[(size_t)(grb + r) * 256 + gc] = f2bf(acc[i][j][r]);
        }
    }
}

// ---------------- bf16 MFMA GEMM (+bias,+lrelu), depth-3 reg rotation -------
__global__ __launch_bounds__(256) void gemm_plain(
    const ushort_t* __restrict__ A, const ushort_t* __restrict__ Bt,
    const float* __restrict__ bias, void* __restrict__ Cout,
    int M, int N, int K, int act, float slope, int outBf) {
    __shared__ __align__(16) ushort_t As[2][128 * 32];
    __shared__ __align__(16) ushort_t Bs[2][128 * 32];
    int t = threadIdx.x;
    int wave = t >> 6, lane = t & 63;
    int wm = (wave >> 1) << 6;
    int wn = (wave & 1) << 6;
    int rowBase = blockIdx.y << 7;
    int colBase = blockIdx.x << 7;
    int lrow = lane & 15, lquad = lane >> 4;
    floatx4 acc[4][4];
#pragma unroll
    for (int i = 0; i < 4; i++)
#pragma unroll
        for (int j = 0; j < 4; j++) acc[i][j] = (floatx4){0.f, 0.f, 0.f, 0.f};

    int c0 = wave * 64 + lane;
    const ushort_t* gA0 = A + (size_t)(rowBase + (c0 >> 2)) * K + ((c0 & 3) << 3);
    const ushort_t* gB0 = Bt + (size_t)(colBase + (c0 >> 2)) * K + ((c0 & 3) << 3);
    int c1 = 256 + c0;
    const ushort_t* gA1 = A + (size_t)(rowBase + (c1 >> 2)) * K + ((c1 & 3) << 3);
    const ushort_t* gB1 = Bt + (size_t)(colBase + (c1 >> 2)) * K + ((c1 & 3) << 3);
    const int wsl0 = (wave * 64 + lane) * 8;
    const int wsl1 = (256 + wave * 64 + lane) * 8;

    const int nt = K >> 5;   // K in {64,256,512} -> nt in {2,8,16}
    DECL_SETS();

    LOADR_S(0, 0);
    LOADR_S(1, 1);
    if (nt > 2) LOADR_S(2, 2);
    WRITER_S(0, 0);
    asm volatile("s_waitcnt lgkmcnt(0)" ::: "memory");
    __builtin_amdgcn_s_barrier();

    for (int kt = 0; kt < nt; ++kt) {
        int b = kt & 1;
        PIPE_STEP(kt, b);
        bf16x8 af[4], bfv[4];
#pragma unroll
        for (int i = 0; i < 4; i++)
            af[i] = *(const bf16x8*)(&As[b][(wm + i * 16 + lrow) * 32 + lquad * 8]);
#pragma unroll
        for (int j = 0; j < 4; j++)
            bfv[j] = *(const bf16x8*)(&Bs[b][(wn + j * 16 + lrow) * 32 + lquad * 8]);
#pragma unroll
        for (int i = 0; i < 4; i++)
#pragma unroll
            for (int j = 0; j < 4; j++)
                acc[i][j] = __builtin_amdgcn_mfma_f32_16x16x32_bf16(af[i], bfv[j],
                                                                    acc[i][j], 0, 0, 0);
        asm volatile("s_waitcnt lgkmcnt(0)" ::: "memory");
        __builtin_amdgcn_s_barrier();
    }

#pragma unroll
    for (int i = 0; i < 4; i++) {
        int gr = rowBase + wm + i * 16 + lquad * 4;
#pragma unroll
        for (int j = 0; j < 4; j++) {
            int gc = colBase + wn + j * 16 + lrow;
            if (gc >= N) continue;
            float b = bias ? bias[gc] : 0.f;
#pragma unroll
            for (int r = 0; r < 4; r++) {
                float v = acc[i][j][r] + b;
                if (act) v = lrelu(v, slope);
                if (outBf)
                    ((ushort_t*)Cout)[(size_t)(gr + r) * N + gc] = f2bf(v);
                else
                    ((float*)Cout)[(size_t)(gr + r) * N + gc] = v;
            }
        }
    }
}

// ---------------- aggregation: TWO nodes per wave, batch-4 gather ------------
// lanes 0-31 -> node A, 32-63 -> node B; 16B/lane (8 channels, ushort8).
__global__ __launch_bounds__(256) void gat_agg(
    const ushort_t* __restrict__ h_bf, const float* __restrict__ al_s,
    const float* __restrict__ al_d, const int* __restrict__ row_ptr,
    const int* __restrict__ col, const float* __restrict__ bias,
    ushort_t* __restrict__ out_bf, int N, int act, float slope) {
    int wid = (blockIdx.x * 256 + threadIdx.x) >> 6;   // wave index
    int lane = threadIdx.x & 63;
    int half = lane >> 5;
    int lane8 = lane & 31;
    int n = wid * 2 + half;
    if (n >= N) return;
    int head = lane8 >> 3;                 // 8 lanes per head, 8 ch per lane
    int idx4 = n * 4 + head;
    float ad = al_d[idx4];
    const ushort8v* h8 = (const ushort8v*)h_bf;   // row stride 32 ushort8
    // self loop
    float p = __expf(lrelu(al_s[idx4] + ad, GAT_SLOPE));
    ushort8v hv = h8[(size_t)n * 32 + lane8];
    float s = p;
    float acc[8];
#pragma unroll
    for (int c = 0; c < 8; c++) acc[c] = p * bf2f(hv[c]);
    int beg = row_ptr[n], end = row_ptr[n + 1];
    for (int i = beg; i < end; i += 4) {
        int cnt = end - i;
        int sn0 = col[i];
        int sn1 = (cnt > 1) ? col[i + 1] : sn0;
        int sn2 = (cnt > 2) ? col[i + 2] : sn0;
        int sn3 = (cnt > 3) ? col[i + 3] : sn0;
        ushort8v h0 = h8[(size_t)sn0 * 32 + lane8];
        ushort8v h1 = h8[(size_t)sn1 * 32 + lane8];
        ushort8v h2 = h8[(size_t)sn2 * 32 + lane8];
        ushort8v h3 = h8[(size_t)sn3 * 32 + lane8];
        float a0 = al_s[sn0 * 4 + head];
        float a1 = al_s[sn1 * 4 + head];
        float a2 = al_s[sn2 * 4 + head];
        float a3 = al_s[sn3 * 4 + head];
        float p0 = __expf(lrelu(a0 + ad, GAT_SLOPE));
#pragma unroll
        for (int c = 0; c < 8; c++) acc[c] += p0 * bf2f(h0[c]);
        s += p0;
        if (cnt > 1) {
            float p1 = __expf(lrelu(a1 + ad, GAT_SLOPE));
#pragma unroll
            for (int c = 0; c < 8; c++) acc[c] += p1 * bf2f(h1[c]);
            s += p1;
        }
        if (cnt > 2) {
            float p2 = __expf(lrelu(a2 + ad, GAT_SLOPE));
#pragma unroll
            for (int c = 0; c < 8; c++) acc[c] += p2 * bf2f(h2[c]);
            s += p2;
        }
        if (cnt > 3) {
            float p3 = __expf(lrelu(a3 + ad, GAT_SLOPE));
#pragma unroll
            for (int c = 0; c < 8; c++) acc[c] += p3 * bf2f(h3[c]);
            s += p3;
        }
    }
    float rs = 1.f / s;
    const float4* b4 = (const float4*)bias;
    float4 b0 = b4[lane8 * 2];
    float4 b1 = b4[lane8 * 2 + 1];
    float bv[8] = {b0.x, b0.y, b0.z, b0.w, b1.x, b1.y, b1.z, b1.w};
    ushort8v o;
#pragma unroll
    for (int c = 0; c < 8; c++) {
        float v = acc[c] * rs + bv[c];
        if (act) v = lrelu(v, slope);
        o[c] = f2bf(v);
    }
    ((ushort8v*)out_bf)[(size_t)n * 32 + lane8] = o;
}

// ---------------------------------------------------------------------------
extern "C" void kernel_launch(void* const* d_in, const int* in_sizes, int n_in,
                              void* d_out, int out_size, void* d_ws, size_t ws_size,
                              hipStream_t stream) {
    const float* x        = (const float*)d_in[0];
    const int*   rawEdge  = (const int*)d_in[1];
    const float* rootCtx  = (const float*)d_in[2];
    const float* W[3]     = {(const float*)d_in[3], (const float*)d_in[7], (const float*)d_in[11]};
    const float* aS[3]    = {(const float*)d_in[4], (const float*)d_in[8], (const float*)d_in[12]};
    const float* aD[3]    = {(const float*)d_in[5], (const float*)d_in[9], (const float*)d_in[13]};
    const float* bb[3]    = {(const float*)d_in[6], (const float*)d_in[10], (const float*)d_in[14]};
    const float* fc_w     = (const float*)d_in[15];
    const float* fc_b     = (const float*)d_in[16];
    const float* r_w1     = (const float*)d_in[17];
    const float* r_b1     = (const float*)d_in[18];
    const float* r_w2     = (const float*)d_in[19];
    const float* r_b2     = (const float*)d_in[20];
    const float* r_w3     = (const float*)d_in[21];
    const float* r_b3     = (const float*)d_in[22];

    const int N  = in_sizes[0] / 80;      // 102400
    const int E  = in_sizes[1] / 2;       // 409600
    const int R  = in_sizes[2] / 60;      // 4096
    const int N4 = N * 4;

    float* outRot  = (float*)d_out;                  // [N, 80]
    float* outRoot = (float*)d_out + (size_t)N * 80; // [R, 60]

    // ---- carve workspace ----
    size_t off = 0;
    auto carve = [&](size_t bytes) -> void* {
        off = (off + 255) & ~(size_t)255;
        void* p = (char*)d_ws + off;
        off += bytes;
        return p;
    };
    int*      flag      = (int*)carve(4);
    int*      idx32     = (int*)carve((size_t)2 * E * 4);
    int*      counts    = (int*)carve((size_t)N * 4);
    int*      cursor    = (int*)carve((size_t)N * 4);
    int*      row_ptr   = (int*)carve((size_t)(N + 1) * 4);
    int*      incArr    = (int*)carve((size_t)N * 4);
    int*      blockSums = (int*)carve(512 * 4);
    int*      colArr    = (int*)carve((size_t)E * 4);
    float*    al_s      = (float*)carve((size_t)N4 * 4);
    float*    al_d      = (float*)carve((size_t)N4 * 4);
    ushort_t* h_bf      = (ushort_t*)carve((size_t)N * 256 * 2);
    ushort_t* agg_bf    = (ushort_t*)carve((size_t)N * 256 * 2);
    ushort_t* x_bf      = (ushort_t*)carve((size_t)N * 96 * 2);    // Kp=96
    ushort_t* rc_bf     = (ushort_t*)carve((size_t)R * 64 * 2);
    ushort_t* t1_bf     = (ushort_t*)carve((size_t)R * 512 * 2);
    ushort_t* t2_bf     = (ushort_t*)carve((size_t)R * 512 * 2);
    ushort_t* Wt0       = (ushort_t*)carve((size_t)256 * 96 * 2);  // Kp=96
    ushort_t* Wt1       = (ushort_t*)carve((size_t)256 * 256 * 2);
    ushort_t* Wt2       = (ushort_t*)carve((size_t)256 * 256 * 2);
    ushort_t* fcWt      = (ushort_t*)carve((size_t)128 * 256 * 2);
    ushort_t* rW1t      = (ushort_t*)carve((size_t)512 * 64 * 2);
    ushort_t* rWt2      = (ushort_t*)carve((size_t)512 * 512 * 2);
    ushort_t* rWt3      = (ushort_t*)carve((size_t)128 * 512 * 2);

    const int nb = (N + 255) / 256;
    dim3 blk(256);

    // ---- edge format + CSR build ----
    detect_fmt<<<1, 256, 0, stream>>>(rawEdge, 2 * E, flag);
    zero2<<<(N + 255) / 256, blk, 0, stream>>>(counts, cursor, N);
    convert_count<<<(E + 255) / 256, blk, 0, stream>>>(rawEdge, E, flag, idx32, counts);
    const int* srcArr = idx32;
    const int* dstArr = idx32 + E;
    scan_block<<<nb, 256, 0, stream>>>(counts, incArr, blockSums, N);
    scan_sums<<<1, 512, 0, stream>>>(blockSums, nb, row_ptr);
    scan_add<<<nb, 256, 0, stream>>>(incArr, blockSums, row_ptr, N);
    edge_fill<<<(E + 255) / 256, blk, 0, stream>>>(srcArr, dstArr, E, row_ptr, cursor, colArr);

    // ---- weight conversions (merged) ----
    {
        WConvArr wa;
        auto mk = [&](int i, const float* in, ushort_t* out, int Kp, int Kr, int Nn, int Npad,
                      int blkOff) {
            wa.e[i] = WConv{in, out, Kp, Kr, Nn, Npad, blkOff};
        };
        int boff = 0;
        auto nblk = [](int Npad, int Kp) { return (Npad * Kp + 255) / 256; };
        mk(0, W[0], Wt0, 96, 80, 256, 256, boff);   boff += nblk(256, 96);
        mk(1, W[1], Wt1, 256, 256, 256, 256, boff); boff += nblk(256, 256);
        mk(2, W[2], Wt2, 256, 256, 256, 256, boff); boff += nblk(256, 256);
        mk(3, fc_w, fcWt, 256, 256, 80, 128, boff); boff += nblk(128, 256);
        mk(4, r_w1, rW1t, 64, 60, 512, 512, boff);  boff += nblk(512, 64);
        mk(5, r_w2, rWt2, 512, 512, 512, 512, boff); boff += nblk(512, 512);
        mk(6, r_w3, rWt3, 512, 512, 60, 128, boff);  boff += nblk(128, 512);
        wa.n = 7;
        convert_w_multi<<<boff, blk, 0, stream>>>(wa);
    }
    convert_padrow<<<(N * 96 + 255) / 256, blk, 0, stream>>>(x, x_bf, N, 80, 96);
    convert_padrow<<<(R * 64 + 255) / 256, blk, 0, stream>>>(rootCtx, rc_bf, R, 60, 64);

    // ---- GAT layers ----
    const int aggBlocks = (N / 2 + 3) / 4;   // 2 nodes/wave, 4 waves/block
    const ushort_t* curA = x_bf;
    int curK = 96;
    for (int l = 0; l < 3; l++) {
        dim3 g1(2, N / 128);
        gemm_gat<<<g1, blk, 0, stream>>>(curA, l == 0 ? Wt0 : (l == 1 ? Wt1 : Wt2),
                                         aS[l], aD[l], h_bf, al_s, al_d, N, curK);
        int act = (l < 2) ? 1 : 0;
        gat_agg<<<aggBlocks, blk, 0, stream>>>(h_bf, al_s, al_d, row_ptr,
                                               colArr, bb[l], agg_bf, N,
                                               act, ACT_SLOPE);
        curA = agg_bf;
        curK = 256;
    }

    // ---- rot = h @ fc_w + fc_b ----
    {
        dim3 g(1, N / 128);
        gemm_plain<<<g, blk, 0, stream>>>(agg_bf, fcWt, fc_b, outRot, N, 80, 256,
                                          0, 0.f, 0);
    }
    // ---- MLP branch (staged MFMA chain) ----
    {
        dim3 g1(512 / 128, R / 128);
        gemm_plain<<<g1, blk, 0, stream>>>(rc_bf, rW1t, r_b1, t1_bf, R, 512, 64,
                                           1, ACT_SLOPE, 1);
        dim3 g2(512 / 128, R / 128);
        gemm_plain<<<g2, blk, 0, stream>>>(t1_bf, rWt2, r_b2, t2_bf, R, 512, 512,
                                           1, ACT_SLOPE, 1);
        dim3 g3(1, R / 128);
        gemm_plain<<<g3, blk, 0, stream>>>(t2_bf, rWt3, r_b3, outRoot, R, 60, 512,
                                           0, 0.f, 0);
    }
}

// Round 11
// 521.267 us; speedup vs baseline: 1.0625x; 1.0625x over previous
//
#include <hip/hip_runtime.h>
#include <hip/hip_bf16.h>

// ---------------------------------------------------------------------------
// GAT x3 + fc + MLP. R21: revert to R19 skeleton (best, 510.8us) and PAIR the
// K-tiles (BK 32->64) in both MFMA GEMMs. Evidence R16/R20: flight depth is
// not the binder; the fixed per-iteration toll (WRITER wait + 2 barriers +
// re-arbitration, ~4.5k cy) is. Pairing halves iteration count, doubles
// per-iter in-flight bytes, zero runtime selects (static regs, rule #20).
// LDS 2x[128x64] = 64KB (2 blocks/CU, matches measured residency).
// Layer-0 K padded 96->128 so all K are multiples of 64 (np in {1,2,4,8}).
// gat_agg = R17 fabric-roofline form (50.3us, leave). CSR/conv unchanged.
// ---------------------------------------------------------------------------

#define GAT_SLOPE 0.2f
#define ACT_SLOPE 0.01f

typedef unsigned short ushort_t;
typedef __attribute__((ext_vector_type(8))) short bf16x8;
typedef __attribute__((ext_vector_type(8))) unsigned short ushort8v;
typedef __attribute__((ext_vector_type(4))) float floatx4;

__device__ __forceinline__ float lrelu(float x, float s) {
    return fmaxf(x, s * x);   // valid for 0<s<1
}

__device__ __forceinline__ ushort_t f2bf(float f) {
    union { float f; unsigned u; } x; x.f = f;
    unsigned r = x.u + 0x7FFF + ((x.u >> 16) & 1);   // round-nearest-even
    return (ushort_t)(r >> 16);
}

__device__ __forceinline__ float bf2f(ushort_t u) {
    union { unsigned u; float f; } x; x.u = ((unsigned)u) << 16;
    return x.f;
}

// ---------------- edge-index format probe ----------------
__global__ void detect_fmt(const int* __restrict__ raw, int nwords, int* flag) {
    __shared__ int nz;
    if (threadIdx.x == 0) nz = 0;
    __syncthreads();
    int lim = nwords < 4096 ? nwords : 4096;
    for (int i = threadIdx.x * 2 + 1; i < lim; i += 512)
        if (raw[i] != 0) atomicAdd(&nz, 1);
    __syncthreads();
    if (threadIdx.x == 0) *flag = (nz == 0) ? 1 : 0;   // 1 => int64 storage
}

__global__ void zero2(int* __restrict__ a, int* __restrict__ b, int n) {
    int i = blockIdx.x * blockDim.x + threadIdx.x;
    if (i < n) { a[i] = 0; b[i] = 0; }
}

__global__ void convert_count(const int* __restrict__ raw, int E,
                              const int* __restrict__ flag,
                              int* __restrict__ idx32, int* __restrict__ counts) {
    int i = blockIdx.x * blockDim.x + threadIdx.x;
    if (i >= E) return;
    int f = *flag;
    int s = f ? raw[2 * i] : raw[i];
    int d = f ? raw[2 * (E + i)] : raw[E + i];
    idx32[i] = s;
    idx32[E + i] = d;
    atomicAdd(&counts[d], 1);
}

__global__ void scan_block(const int* __restrict__ counts, int* __restrict__ inc,
                           int* __restrict__ blockSums, int N) {
    __shared__ int sh[256];
    int i = blockIdx.x * 256 + threadIdx.x;
    int v = (i < N) ? counts[i] : 0;
    sh[threadIdx.x] = v;
    __syncthreads();
    for (int off = 1; off < 256; off <<= 1) {
        int t = (threadIdx.x >= off) ? sh[threadIdx.x - off] : 0;
        __syncthreads();
        sh[threadIdx.x] += t;
        __syncthreads();
    }
    if (i < N) inc[i] = sh[threadIdx.x];
    if (threadIdx.x == 255) blockSums[blockIdx.x] = sh[255];
}

__global__ void scan_sums(int* __restrict__ blockSums, int nb, int* __restrict__ row_ptr) {
    __shared__ int sh[512];
    int v = ((int)threadIdx.x < nb) ? blockSums[threadIdx.x] : 0;
    sh[threadIdx.x] = v;
    __syncthreads();
    for (int off = 1; off < 512; off <<= 1) {
        int t = (threadIdx.x >= off) ? sh[threadIdx.x - off] : 0;
        __syncthreads();
        sh[threadIdx.x] += t;
        __syncthreads();
    }
    if ((int)threadIdx.x < nb) blockSums[threadIdx.x] = sh[threadIdx.x];
    if (threadIdx.x == 0) row_ptr[0] = 0;
}

__global__ void scan_add(const int* __restrict__ inc, const int* __restrict__ blockSums,
                         int* __restrict__ row_ptr, int N) {
    int i = blockIdx.x * 256 + threadIdx.x;
    if (i < N) row_ptr[i + 1] = inc[i] + (blockIdx.x > 0 ? blockSums[blockIdx.x - 1] : 0);
}

__global__ void edge_fill(const int* __restrict__ src, const int* __restrict__ dst, int E,
                          const int* __restrict__ row_ptr, int* __restrict__ cursor,
                          int* __restrict__ col) {
    int i = blockIdx.x * blockDim.x + threadIdx.x;
    if (i < E) {
        int d = dst[i];
        int pos = row_ptr[d] + atomicAdd(&cursor[d], 1);
        col[pos] = src[i];
    }
}

// ---------------- conversions ----------------
__global__ void convert_padrow(const float* __restrict__ in, ushort_t* __restrict__ out,
                               int M, int Kr, int Kp) {
    int i = blockIdx.x * blockDim.x + threadIdx.x;
    if (i >= M * Kp) return;
    int r = i / Kp, c = i - r * Kp;
    out[i] = f2bf((c < Kr) ? in[(size_t)r * Kr + c] : 0.f);
}

struct WConv { const float* in; ushort_t* out; int Kp, Kr, N, Npad, blkOff; };
struct WConvArr { WConv e[7]; int n; };

__global__ void convert_w_multi(WConvArr a) {
    int b = blockIdx.x;
    int ei = 0;
    for (int k = 1; k < a.n; k++)
        if (b >= a.e[k].blkOff) ei = k;
    WConv w = a.e[ei];
    int i = (b - w.blkOff) * 256 + threadIdx.x;
    if (i >= w.Npad * w.Kp) return;
    int n = i / w.Kp, k = i - n * w.Kp;
    float v = (n < w.N && k < w.Kr) ? w.in[(size_t)k * w.N + n] : 0.f;
    w.out[i] = f2bf(v);
}

// ---- paired-tile (BK=64) staging macros: 8 static regs, no selects --------
#define DECL_P()                                      \
    ushort8v pa0, pa1, pb0, pb1, qa0, qa1, qb0, qb1

#define LOADP(pp)                                     \
    do {                                              \
        int k0_ = (pp) << 6;                          \
        pa0 = *(const ushort8v*)(gA0 + k0_);          \
        pa1 = *(const ushort8v*)(gA1 + k0_);          \
        pb0 = *(const ushort8v*)(gB0 + k0_);          \
        pb1 = *(const ushort8v*)(gB1 + k0_);          \
        qa0 = *(const ushort8v*)(gA0 + k0_ + 32);     \
        qa1 = *(const ushort8v*)(gA1 + k0_ + 32);     \
        qb0 = *(const ushort8v*)(gB0 + k0_ + 32);     \
        qb1 = *(const ushort8v*)(gB1 + k0_ + 32);     \
    } while (0)

#define WRITEP(b)                                     \
    do {                                              \
        *(ushort8v*)(&As[b][wsl0]) = pa0;             \
        *(ushort8v*)(&As[b][wsl1]) = pa1;             \
        *(ushort8v*)(&Bs[b][wsl0]) = pb0;             \
        *(ushort8v*)(&Bs[b][wsl1]) = pb1;             \
        *(ushort8v*)(&As[b][4096 + wsl0]) = qa0;      \
        *(ushort8v*)(&As[b][4096 + wsl1]) = qa1;      \
        *(ushort8v*)(&Bs[b][4096 + wsl0]) = qb0;      \
        *(ushort8v*)(&Bs[b][4096 + wsl1]) = qb1;      \
    } while (0)

#define MFMA_SUB(b, base)                                                        \
    do {                                                                         \
        bf16x8 af[4], bfv[4];                                                    \
        _Pragma("unroll")                                                        \
        for (int i = 0; i < 4; i++)                                              \
            af[i] = *(const bf16x8*)(&As[b][(base) + (wm + i * 16 + lrow) * 32   \
                                            + lquad * 8]);                       \
        _Pragma("unroll")                                                        \
        for (int j = 0; j < 4; j++)                                              \
            bfv[j] = *(const bf16x8*)(&Bs[b][(base) + (wn + j * 16 + lrow) * 32  \
                                             + lquad * 8]);                      \
        _Pragma("unroll")                                                        \
        for (int i = 0; i < 4; i++)                                              \
            _Pragma("unroll")                                                    \
            for (int j = 0; j < 4; j++)                                          \
                acc[i][j] = __builtin_amdgcn_mfma_f32_16x16x32_bf16(             \
                    af[i], bfv[j], acc[i][j], 0, 0, 0);                          \
    } while (0)

// ---------------- GAT GEMM: paired tiles, reg-staged, 1 barrier/pair -------
__global__ __launch_bounds__(256) void gemm_gat(
    const ushort_t* __restrict__ A, const ushort_t* __restrict__ Bt,
    const float* __restrict__ a_src, const float* __restrict__ a_dst,
    ushort_t* __restrict__ Hbf, float* __restrict__ al_s, float* __restrict__ al_d,
    int M, int K) {
    __shared__ __align__(16) ushort_t As[2][128 * 64];
    __shared__ __align__(16) ushort_t Bs[2][128 * 64];
    int t = threadIdx.x;
    int wave = t >> 6, lane = t & 63;
    int wm = (wave >> 1) << 6;
    int wn = (wave & 1) << 6;
    int rowBase = blockIdx.y << 7;
    int colBase = blockIdx.x << 7;
    int lrow = lane & 15, lquad = lane >> 4;
    floatx4 acc[4][4];
#pragma unroll
    for (int i = 0; i < 4; i++)
#pragma unroll
        for (int j = 0; j < 4; j++) acc[i][j] = (floatx4){0.f, 0.f, 0.f, 0.f};

    int c0 = wave * 64 + lane;
    const ushort_t* gA0 = A + (size_t)(rowBase + (c0 >> 2)) * K + ((c0 & 3) << 3);
    const ushort_t* gB0 = Bt + (size_t)(colBase + (c0 >> 2)) * K + ((c0 & 3) << 3);
    int c1 = 256 + c0;
    const ushort_t* gA1 = A + (size_t)(rowBase + (c1 >> 2)) * K + ((c1 & 3) << 3);
    const ushort_t* gB1 = Bt + (size_t)(colBase + (c1 >> 2)) * K + ((c1 & 3) << 3);
    const int wsl0 = (wave * 64 + lane) * 8;
    const int wsl1 = (256 + wave * 64 + lane) * 8;

    const int np = K >> 6;   // K in {128,256} -> np in {2,4}
    DECL_P();

    LOADP(0);
    WRITEP(0);                 // compiler waits pair-0 loads
    if (np > 1) LOADP(1);
    asm volatile("s_waitcnt lgkmcnt(0)" ::: "memory");
    __builtin_amdgcn_s_barrier();

    for (int kp = 0; kp < np; ++kp) {
        int b = kp & 1;
        if (kp + 1 < np) WRITEP(b ^ 1);    // stage pair kp+1 (waits its loads)
        if (kp + 2 < np) LOADP(kp + 2);    // refill regs; 1 pair-iter flight
        MFMA_SUB(b, 0);
        MFMA_SUB(b, 4096);
        asm volatile("s_waitcnt lgkmcnt(0)" ::: "memory");
        __builtin_amdgcn_s_barrier();
    }

    // epilogue: al_s/al_d per (row, head) + bf16 h store (NCOL=256)
    int head = (colBase + wn) >> 6;
    float avs[4], avd[4];
#pragma unroll
    for (int j = 0; j < 4; j++) {
        avs[j] = a_src[head * 64 + j * 16 + lrow];
        avd[j] = a_dst[head * 64 + j * 16 + lrow];
    }
#pragma unroll
    for (int i = 0; i < 4; i++) {
#pragma unroll
        for (int r = 0; r < 4; r++) {
            float ps = 0.f, pd = 0.f;
#pragma unroll
            for (int j = 0; j < 4; j++) {
                ps += acc[i][j][r] * avs[j];
                pd += acc[i][j][r] * avd[j];
            }
#pragma unroll
            for (int off = 1; off < 16; off <<= 1) {
                ps += __shfl_xor(ps, off);
                pd += __shfl_xor(pd, off);
            }
            if (lrow == 0) {
                int gr = rowBase + wm + i * 16 + lquad * 4 + r;
                al_s[gr * 4 + head] = ps;
                al_d[gr * 4 + head] = pd;
            }
        }
        int grb = rowBase + wm + i * 16 + lquad * 4;
#pragma unroll
        for (int j = 0; j < 4; j++) {
            int gc = colBase + wn + j * 16 + lrow;
#pragma unroll
            for (int r = 0; r < 4; r++)
                Hbf[(size_t)(grb + r) * 256 + gc] = f2bf(acc[i][j][r]);
        }
    }
}

// ---------------- bf16 MFMA GEMM (+bias,+lrelu), paired tiles ---------------
__global__ __launch_bounds__(256) void gemm_plain(
    const ushort_t* __restrict__ A, const ushort_t* __restrict__ Bt,
    const float* __restrict__ bias, void* __restrict__ Cout,
    int M, int N, int K, int act, float slope, int outBf) {
    __shared__ __align__(16) ushort_t As[2][128 * 64];
    __shared__ __align__(16) ushort_t Bs[2][128 * 64];
    int t = threadIdx.x;
    int wave = t >> 6, lane = t & 63;
    int wm = (wave >> 1) << 6;
    int wn = (wave & 1) << 6;
    int rowBase = blockIdx.y << 7;
    int colBase = blockIdx.x << 7;
    int lrow = lane & 15, lquad = lane >> 4;
    floatx4 acc[4][4];
#pragma unroll
    for (int i = 0; i < 4; i++)
#pragma unroll
        for (int j = 0; j < 4; j++) acc[i][j] = (floatx4){0.f, 0.f, 0.f, 0.f};

    int c0 = wave * 64 + lane;
    const ushort_t* gA0 = A + (size_t)(rowBase + (c0 >> 2)) * K + ((c0 & 3) << 3);
    const ushort_t* gB0 = Bt + (size_t)(colBase + (c0 >> 2)) * K + ((c0 & 3) << 3);
    int c1 = 256 + c0;
    const ushort_t* gA1 = A + (size_t)(rowBase + (c1 >> 2)) * K + ((c1 & 3) << 3);
    const ushort_t* gB1 = Bt + (size_t)(colBase + (c1 >> 2)) * K + ((c1 & 3) << 3);
    const int wsl0 = (wave * 64 + lane) * 8;
    const int wsl1 = (256 + wave * 64 + lane) * 8;

    const int np = K >> 6;   // K in {64,256,512} -> np in {1,4,8}
    DECL_P();

    LOADP(0);
    WRITEP(0);
    if (np > 1) LOADP(1);
    asm volatile("s_waitcnt lgkmcnt(0)" ::: "memory");
    __builtin_amdgcn_s_barrier();

    for (int kp = 0; kp < np; ++kp) {
        int b = kp & 1;
        if (kp + 1 < np) WRITEP(b ^ 1);
        if (kp + 2 < np) LOADP(kp + 2);
        MFMA_SUB(b, 0);
        MFMA_SUB(b, 4096);
        asm volatile("s_waitcnt lgkmcnt(0)" ::: "memory");
        __builtin_amdgcn_s_barrier();
    }

#pragma unroll
    for (int i = 0; i < 4; i++) {
        int gr = rowBase + wm + i * 16 + lquad * 4;
#pragma unroll
        for (int j = 0; j < 4; j++) {
            int gc = colBase + wn + j * 16 + lrow;
            if (gc >= N) continue;
            float b = bias ? bias[gc] : 0.f;
#pragma unroll
            for (int r = 0; r < 4; r++) {
                float v = acc[i][j][r] + b;
                if (act) v = lrelu(v, slope);
                if (outBf)
                    ((ushort_t*)Cout)[(size_t)(gr + r) * N + gc] = f2bf(v);
                else
                    ((float*)Cout)[(size_t)(gr + r) * N + gc] = v;
            }
        }
    }
}

// ---------------- aggregation: TWO nodes per wave, batch-4 gather ------------
// lanes 0-31 -> node A, 32-63 -> node B; 16B/lane (8 channels, ushort8).
__global__ __launch_bounds__(256) void gat_agg(
    const ushort_t* __restrict__ h_bf, const float* __restrict__ al_s,
    const float* __restrict__ al_d, const int* __restrict__ row_ptr,
    const int* __restrict__ col, const float* __restrict__ bias,
    ushort_t* __restrict__ out_bf, int N, int act, float slope) {
    int wid = (blockIdx.x * 256 + threadIdx.x) >> 6;   // wave index
    int lane = threadIdx.x & 63;
    int half = lane >> 5;
    int lane8 = lane & 31;
    int n = wid * 2 + half;
    if (n >= N) return;
    int head = lane8 >> 3;                 // 8 lanes per head, 8 ch per lane
    int idx4 = n * 4 + head;
    float ad = al_d[idx4];
    const ushort8v* h8 = (const ushort8v*)h_bf;   // row stride 32 ushort8
    // self loop
    float p = __expf(lrelu(al_s[idx4] + ad, GAT_SLOPE));
    ushort8v hv = h8[(size_t)n * 32 + lane8];
    float s = p;
    float acc[8];
#pragma unroll
    for (int c = 0; c < 8; c++) acc[c] = p * bf2f(hv[c]);
    int beg = row_ptr[n], end = row_ptr[n + 1];
    for (int i = beg; i < end; i += 4) {
        int cnt = end - i;
        int sn0 = col[i];
        int sn1 = (cnt > 1) ? col[i + 1] : sn0;
        int sn2 = (cnt > 2) ? col[i + 2] : sn0;
        int sn3 = (cnt > 3) ? col[i + 3] : sn0;
        ushort8v h0 = h8[(size_t)sn0 * 32 + lane8];
        ushort8v h1 = h8[(size_t)sn1 * 32 + lane8];
        ushort8v h2 = h8[(size_t)sn2 * 32 + lane8];
        ushort8v h3 = h8[(size_t)sn3 * 32 + lane8];
        float a0 = al_s[sn0 * 4 + head];
        float a1 = al_s[sn1 * 4 + head];
        float a2 = al_s[sn2 * 4 + head];
        float a3 = al_s[sn3 * 4 + head];
        float p0 = __expf(lrelu(a0 + ad, GAT_SLOPE));
#pragma unroll
        for (int c = 0; c < 8; c++) acc[c] += p0 * bf2f(h0[c]);
        s += p0;
        if (cnt > 1) {
            float p1 = __expf(lrelu(a1 + ad, GAT_SLOPE));
#pragma unroll
            for (int c = 0; c < 8; c++) acc[c] += p1 * bf2f(h1[c]);
            s += p1;
        }
        if (cnt > 2) {
            float p2 = __expf(lrelu(a2 + ad, GAT_SLOPE));
#pragma unroll
            for (int c = 0; c < 8; c++) acc[c] += p2 * bf2f(h2[c]);
            s += p2;
        }
        if (cnt > 3) {
            float p3 = __expf(lrelu(a3 + ad, GAT_SLOPE));
#pragma unroll
            for (int c = 0; c < 8; c++) acc[c] += p3 * bf2f(h3[c]);
            s += p3;
        }
    }
    float rs = 1.f / s;
    const float4* b4 = (const float4*)bias;
    float4 b0 = b4[lane8 * 2];
    float4 b1 = b4[lane8 * 2 + 1];
    float bv[8] = {b0.x, b0.y, b0.z, b0.w, b1.x, b1.y, b1.z, b1.w};
    ushort8v o;
#pragma unroll
    for (int c = 0; c < 8; c++) {
        float v = acc[c] * rs + bv[c];
        if (act) v = lrelu(v, slope);
        o[c] = f2bf(v);
    }
    ((ushort8v*)out_bf)[(size_t)n * 32 + lane8] = o;
}

// ---------------------------------------------------------------------------
extern "C" void kernel_launch(void* const* d_in, const int* in_sizes, int n_in,
                              void* d_out, int out_size, void* d_ws, size_t ws_size,
                              hipStream_t stream) {
    const float* x        = (const float*)d_in[0];
    const int*   rawEdge  = (const int*)d_in[1];
    const float* rootCtx  = (const float*)d_in[2];
    const float* W[3]     = {(const float*)d_in[3], (const float*)d_in[7], (const float*)d_in[11]};
    const float* aS[3]    = {(const float*)d_in[4], (const float*)d_in[8], (const float*)d_in[12]};
    const float* aD[3]    = {(const float*)d_in[5], (const float*)d_in[9], (const float*)d_in[13]};
    const float* bb[3]    = {(const float*)d_in[6], (const float*)d_in[10], (const float*)d_in[14]};
    const float* fc_w     = (const float*)d_in[15];
    const float* fc_b     = (const float*)d_in[16];
    const float* r_w1     = (const float*)d_in[17];
    const float* r_b1     = (const float*)d_in[18];
    const float* r_w2     = (const float*)d_in[19];
    const float* r_b2     = (const float*)d_in[20];
    const float* r_w3     = (const float*)d_in[21];
    const float* r_b3     = (const float*)d_in[22];

    const int N  = in_sizes[0] / 80;      // 102400
    const int E  = in_sizes[1] / 2;       // 409600
    const int R  = in_sizes[2] / 60;      // 4096
    const int N4 = N * 4;

    float* outRot  = (float*)d_out;                  // [N, 80]
    float* outRoot = (float*)d_out + (size_t)N * 80; // [R, 60]

    // ---- carve workspace ----
    size_t off = 0;
    auto carve = [&](size_t bytes) -> void* {
        off = (off + 255) & ~(size_t)255;
        void* p = (char*)d_ws + off;
        off += bytes;
        return p;
    };
    int*      flag      = (int*)carve(4);
    int*      idx32     = (int*)carve((size_t)2 * E * 4);
    int*      counts    = (int*)carve((size_t)N * 4);
    int*      cursor    = (int*)carve((size_t)N * 4);
    int*      row_ptr   = (int*)carve((size_t)(N + 1) * 4);
    int*      incArr    = (int*)carve((size_t)N * 4);
    int*      blockSums = (int*)carve(512 * 4);
    int*      colArr    = (int*)carve((size_t)E * 4);
    float*    al_s      = (float*)carve((size_t)N4 * 4);
    float*    al_d      = (float*)carve((size_t)N4 * 4);
    ushort_t* h_bf      = (ushort_t*)carve((size_t)N * 256 * 2);
    ushort_t* agg_bf    = (ushort_t*)carve((size_t)N * 256 * 2);
    ushort_t* x_bf      = (ushort_t*)carve((size_t)N * 128 * 2);   // Kp=128
    ushort_t* rc_bf     = (ushort_t*)carve((size_t)R * 64 * 2);
    ushort_t* t1_bf     = (ushort_t*)carve((size_t)R * 512 * 2);
    ushort_t* t2_bf     = (ushort_t*)carve((size_t)R * 512 * 2);
    ushort_t* Wt0       = (ushort_t*)carve((size_t)256 * 128 * 2); // Kp=128
    ushort_t* Wt1       = (ushort_t*)carve((size_t)256 * 256 * 2);
    ushort_t* Wt2       = (ushort_t*)carve((size_t)256 * 256 * 2);
    ushort_t* fcWt      = (ushort_t*)carve((size_t)128 * 256 * 2);
    ushort_t* rW1t      = (ushort_t*)carve((size_t)512 * 64 * 2);
    ushort_t* rWt2      = (ushort_t*)carve((size_t)512 * 512 * 2);
    ushort_t* rWt3      = (ushort_t*)carve((size_t)128 * 512 * 2);

    const int nb = (N + 255) / 256;
    dim3 blk(256);

    // ---- edge format + CSR build ----
    detect_fmt<<<1, 256, 0, stream>>>(rawEdge, 2 * E, flag);
    zero2<<<(N + 255) / 256, blk, 0, stream>>>(counts, cursor, N);
    convert_count<<<(E + 255) / 256, blk, 0, stream>>>(rawEdge, E, flag, idx32, counts);
    const int* srcArr = idx32;
    const int* dstArr = idx32 + E;
    scan_block<<<nb, 256, 0, stream>>>(counts, incArr, blockSums, N);
    scan_sums<<<1, 512, 0, stream>>>(blockSums, nb, row_ptr);
    scan_add<<<nb, 256, 0, stream>>>(incArr, blockSums, row_ptr, N);
    edge_fill<<<(E + 255) / 256, blk, 0, stream>>>(srcArr, dstArr, E, row_ptr, cursor, colArr);

    // ---- weight conversions (merged) ----
    {
        WConvArr wa;
        auto mk = [&](int i, const float* in, ushort_t* out, int Kp, int Kr, int Nn, int Npad,
                      int blkOff) {
            wa.e[i] = WConv{in, out, Kp, Kr, Nn, Npad, blkOff};
        };
        int boff = 0;
        auto nblk = [](int Npad, int Kp) { return (Npad * Kp + 255) / 256; };
        mk(0, W[0], Wt0, 128, 80, 256, 256, boff);  boff += nblk(256, 128);
        mk(1, W[1], Wt1, 256, 256, 256, 256, boff); boff += nblk(256, 256);
        mk(2, W[2], Wt2, 256, 256, 256, 256, boff); boff += nblk(256, 256);
        mk(3, fc_w, fcWt, 256, 256, 80, 128, boff); boff += nblk(128, 256);
        mk(4, r_w1, rW1t, 64, 60, 512, 512, boff);  boff += nblk(512, 64);
        mk(5, r_w2, rWt2, 512, 512, 512, 512, boff); boff += nblk(512, 512);
        mk(6, r_w3, rWt3, 512, 512, 60, 128, boff);  boff += nblk(128, 512);
        wa.n = 7;
        convert_w_multi<<<boff, blk, 0, stream>>>(wa);
    }
    convert_padrow<<<(N * 128 + 255) / 256, blk, 0, stream>>>(x, x_bf, N, 80, 128);
    convert_padrow<<<(R * 64 + 255) / 256, blk, 0, stream>>>(rootCtx, rc_bf, R, 60, 64);

    // ---- GAT layers ----
    const int aggBlocks = (N / 2 + 3) / 4;   // 2 nodes/wave, 4 waves/block
    const ushort_t* curA = x_bf;
    int curK = 128;
    for (int l = 0; l < 3; l++) {
        dim3 g1(2, N / 128);
        gemm_gat<<<g1, blk, 0, stream>>>(curA, l == 0 ? Wt0 : (l == 1 ? Wt1 : Wt2),
                                         aS[l], aD[l], h_bf, al_s, al_d, N, curK);
        int act = (l < 2) ? 1 : 0;
        gat_agg<<<aggBlocks, blk, 0, stream>>>(h_bf, al_s, al_d, row_ptr,
                                               colArr, bb[l], agg_bf, N,
                                               act, ACT_SLOPE);
        curA = agg_bf;
        curK = 256;
    }

    // ---- rot = h @ fc_w + fc_b ----
    {
        dim3 g(1, N / 128);
        gemm_plain<<<g, blk, 0, stream>>>(agg_bf, fcWt, fc_b, outRot, N, 80, 256,
                                          0, 0.f, 0);
    }
    // ---- MLP branch (staged MFMA chain) ----
    {
        dim3 g1(512 / 128, R / 128);
        gemm_plain<<<g1, blk, 0, stream>>>(rc_bf, rW1t, r_b1, t1_bf, R, 512, 64,
                                           1, ACT_SLOPE, 1);
        dim3 g2(512 / 128, R / 128);
        gemm_plain<<<g2, blk, 0, stream>>>(t1_bf, rWt2, r_b2, t2_bf, R, 512, 512,
                                           1, ACT_SLOPE, 1);
        dim3 g3(1, R / 128);
        gemm_plain<<<g3, blk, 0, stream>>>(t2_bf, rWt3, r_b3, outRoot, R, 60, 512,
                                           0, 0.f, 0);
    }
}

// Round 12
// 481.251 us; speedup vs baseline: 1.1509x; 1.0832x over previous
//
#include <hip/hip_runtime.h>
#include <hip/hip_bf16.h>

// ---------------------------------------------------------------------------
// GAT x3 + fc + MLP. R22: revert GEMMs to R19 skeleton (best, 510.8us) and
// FUSE the 3-layer MLP chain into the 3 gemm_gat launches as auxiliary tail
// blocks (by >= yMain -> plain-GEMM path, same LDS/pipeline). The MLP GEMMs
// ran on 32-128-block grids (5-50% CU util) as serial dispatches; fusing
// hides them in gemm_gat's tail and removes 3 launch gaps. Stream order
// preserves deps: MLP1 under GAT-l0, MLP2 under l1, MLP3 under l2.
// fc separate (needs final agg). gat_agg = R17 fabric-roofline form.
// GEMM-loop evidence ledger: reg-staging WIN (R17); depth/pairing variants
// all null/neg (R14,R16,R20,R21) -> loop structure frozen at R19 form.
// ---------------------------------------------------------------------------

#define GAT_SLOPE 0.2f
#define ACT_SLOPE 0.01f

typedef unsigned short ushort_t;
typedef __attribute__((ext_vector_type(8))) short bf16x8;
typedef __attribute__((ext_vector_type(8))) unsigned short ushort8v;
typedef __attribute__((ext_vector_type(4))) float floatx4;

__device__ __forceinline__ float lrelu(float x, float s) {
    return fmaxf(x, s * x);   // valid for 0<s<1
}

__device__ __forceinline__ ushort_t f2bf(float f) {
    union { float f; unsigned u; } x; x.f = f;
    unsigned r = x.u + 0x7FFF + ((x.u >> 16) & 1);   // round-nearest-even
    return (ushort_t)(r >> 16);
}

__device__ __forceinline__ float bf2f(ushort_t u) {
    union { unsigned u; float f; } x; x.u = ((unsigned)u) << 16;
    return x.f;
}

// ---------------- edge-index format probe ----------------
__global__ void detect_fmt(const int* __restrict__ raw, int nwords, int* flag) {
    __shared__ int nz;
    if (threadIdx.x == 0) nz = 0;
    __syncthreads();
    int lim = nwords < 4096 ? nwords : 4096;
    for (int i = threadIdx.x * 2 + 1; i < lim; i += 512)
        if (raw[i] != 0) atomicAdd(&nz, 1);
    __syncthreads();
    if (threadIdx.x == 0) *flag = (nz == 0) ? 1 : 0;   // 1 => int64 storage
}

__global__ void zero2(int* __restrict__ a, int* __restrict__ b, int n) {
    int i = blockIdx.x * blockDim.x + threadIdx.x;
    if (i < n) { a[i] = 0; b[i] = 0; }
}

__global__ void convert_count(const int* __restrict__ raw, int E,
                              const int* __restrict__ flag,
                              int* __restrict__ idx32, int* __restrict__ counts) {
    int i = blockIdx.x * blockDim.x + threadIdx.x;
    if (i >= E) return;
    int f = *flag;
    int s = f ? raw[2 * i] : raw[i];
    int d = f ? raw[2 * (E + i)] : raw[E + i];
    idx32[i] = s;
    idx32[E + i] = d;
    atomicAdd(&counts[d], 1);
}

__global__ void scan_block(const int* __restrict__ counts, int* __restrict__ inc,
                           int* __restrict__ blockSums, int N) {
    __shared__ int sh[256];
    int i = blockIdx.x * 256 + threadIdx.x;
    int v = (i < N) ? counts[i] : 0;
    sh[threadIdx.x] = v;
    __syncthreads();
    for (int off = 1; off < 256; off <<= 1) {
        int t = (threadIdx.x >= off) ? sh[threadIdx.x - off] : 0;
        __syncthreads();
        sh[threadIdx.x] += t;
        __syncthreads();
    }
    if (i < N) inc[i] = sh[threadIdx.x];
    if (threadIdx.x == 255) blockSums[blockIdx.x] = sh[255];
}

__global__ void scan_sums(int* __restrict__ blockSums, int nb, int* __restrict__ row_ptr) {
    __shared__ int sh[512];
    int v = ((int)threadIdx.x < nb) ? blockSums[threadIdx.x] : 0;
    sh[threadIdx.x] = v;
    __syncthreads();
    for (int off = 1; off < 512; off <<= 1) {
        int t = (threadIdx.x >= off) ? sh[threadIdx.x - off] : 0;
        __syncthreads();
        sh[threadIdx.x] += t;
        __syncthreads();
    }
    if ((int)threadIdx.x < nb) blockSums[threadIdx.x] = sh[threadIdx.x];
    if (threadIdx.x == 0) row_ptr[0] = 0;
}

__global__ void scan_add(const int* __restrict__ inc, const int* __restrict__ blockSums,
                         int* __restrict__ row_ptr, int N) {
    int i = blockIdx.x * 256 + threadIdx.x;
    if (i < N) row_ptr[i + 1] = inc[i] + (blockIdx.x > 0 ? blockSums[blockIdx.x - 1] : 0);
}

__global__ void edge_fill(const int* __restrict__ src, const int* __restrict__ dst, int E,
                          const int* __restrict__ row_ptr, int* __restrict__ cursor,
                          int* __restrict__ col) {
    int i = blockIdx.x * blockDim.x + threadIdx.x;
    if (i < E) {
        int d = dst[i];
        int pos = row_ptr[d] + atomicAdd(&cursor[d], 1);
        col[pos] = src[i];
    }
}

// ---------------- conversions ----------------
__global__ void convert_padrow(const float* __restrict__ in, ushort_t* __restrict__ out,
                               int M, int Kr, int Kp) {
    int i = blockIdx.x * blockDim.x + threadIdx.x;
    if (i >= M * Kp) return;
    int r = i / Kp, c = i - r * Kp;
    out[i] = f2bf((c < Kr) ? in[(size_t)r * Kr + c] : 0.f);
}

struct WConv { const float* in; ushort_t* out; int Kp, Kr, N, Npad, blkOff; };
struct WConvArr { WConv e[7]; int n; };

__global__ void convert_w_multi(WConvArr a) {
    int b = blockIdx.x;
    int ei = 0;
    for (int k = 1; k < a.n; k++)
        if (b >= a.e[k].blkOff) ei = k;
    WConv w = a.e[ei];
    int i = (b - w.blkOff) * 256 + threadIdx.x;
    if (i >= w.Npad * w.Kp) return;
    int n = i / w.Kp, k = i - n * w.Kp;
    float v = (n < w.N && k < w.Kr) ? w.in[(size_t)k * w.N + n] : 0.f;
    w.out[i] = f2bf(v);
}

// ---- R19 reg-staged pipeline macros (proven best loop structure) ----------
#define LOADR(tt)                                     \
    do {                                              \
        int k0_ = (tt) << 5;                          \
        rA0 = *(const ushort8v*)(gA0 + k0_);          \
        rA1 = *(const ushort8v*)(gA1 + k0_);          \
        rB0 = *(const ushort8v*)(gB0 + k0_);          \
        rB1 = *(const ushort8v*)(gB1 + k0_);          \
    } while (0)

#define WRITER(b)                                     \
    do {                                              \
        *(ushort8v*)(&As[b][wsl0]) = rA0;             \
        *(ushort8v*)(&As[b][wsl1]) = rA1;             \
        *(ushort8v*)(&Bs[b][wsl0]) = rB0;             \
        *(ushort8v*)(&Bs[b][wsl1]) = rB1;             \
    } while (0)

#define GEMM_PIPELINE(NT)                                                        \
    ushort8v rA0, rA1, rB0, rB1;                                                 \
    LOADR(0);                                                                    \
    WRITER(0);                                                                   \
    LOADR(1);                                                                    \
    asm volatile("s_waitcnt lgkmcnt(0)" ::: "memory");                           \
    __builtin_amdgcn_s_barrier();                                                \
    for (int kt = 0; kt < (NT); ++kt) {                                          \
        int b = kt & 1;                                                          \
        if (kt + 1 < (NT)) WRITER(b ^ 1);                                        \
        if (kt + 2 < (NT)) LOADR(kt + 2);                                        \
        bf16x8 af[4], bfv[4];                                                    \
        _Pragma("unroll")                                                        \
        for (int i = 0; i < 4; i++)                                              \
            af[i] = *(const bf16x8*)(&As[b][(wm + i * 16 + lrow) * 32            \
                                            + lquad * 8]);                       \
        _Pragma("unroll")                                                        \
        for (int j = 0; j < 4; j++)                                              \
            bfv[j] = *(const bf16x8*)(&Bs[b][(wn + j * 16 + lrow) * 32           \
                                             + lquad * 8]);                      \
        _Pragma("unroll")                                                        \
        for (int i = 0; i < 4; i++)                                              \
            _Pragma("unroll")                                                    \
            for (int j = 0; j < 4; j++)                                          \
                acc[i][j] = __builtin_amdgcn_mfma_f32_16x16x32_bf16(             \
                    af[i], bfv[j], acc[i][j], 0, 0, 0);                          \
        asm volatile("s_waitcnt lgkmcnt(0)" ::: "memory");                       \
        __builtin_amdgcn_s_barrier();                                            \
    }

// ---------------- unified GAT GEMM + auxiliary MLP GEMM tail ---------------
// blocks with by < yMain: GAT GEMM (h = A@W, al_s/al_d epilogue).
// blocks with by >= yMain: one MLP-chain GEMM layer (plain +bias+lrelu),
// remapped to a logical (xGX x xGY) grid. Runs on the tail CUs of the big
// GAT launch; consumed only after this kernel completes (stream order).
__global__ __launch_bounds__(256) void gemm_gat(
    const ushort_t* __restrict__ A, const ushort_t* __restrict__ Bt,
    const float* __restrict__ a_src, const float* __restrict__ a_dst,
    ushort_t* __restrict__ Hbf, float* __restrict__ al_s, float* __restrict__ al_d,
    int K, int yMain,
    const ushort_t* __restrict__ xA, const ushort_t* __restrict__ xBt,
    const float* __restrict__ xBias, void* __restrict__ xC,
    int xN, int xK, int xGX, int xCnt, int xAct, float xSlope, int xOutBf) {
    __shared__ __align__(16) ushort_t As[2][128 * 32];
    __shared__ __align__(16) ushort_t Bs[2][128 * 32];
    int t = threadIdx.x;
    int wave = t >> 6, lane = t & 63;
    int wm = (wave >> 1) << 6;
    int wn = (wave & 1) << 6;
    int lrow = lane & 15, lquad = lane >> 4;
    const int wsl0 = (wave * 64 + lane) * 8;
    const int wsl1 = (256 + wave * 64 + lane) * 8;
    int c0 = wave * 64 + lane;
    int c1 = 256 + c0;

    floatx4 acc[4][4];
#pragma unroll
    for (int i = 0; i < 4; i++)
#pragma unroll
        for (int j = 0; j < 4; j++) acc[i][j] = (floatx4){0.f, 0.f, 0.f, 0.f};

    if ((int)blockIdx.y < yMain) {
        // ---------------- GAT path ----------------
        int rowBase = blockIdx.y << 7;
        int colBase = blockIdx.x << 7;
        const ushort_t* gA0 = A + (size_t)(rowBase + (c0 >> 2)) * K + ((c0 & 3) << 3);
        const ushort_t* gB0 = Bt + (size_t)(colBase + (c0 >> 2)) * K + ((c0 & 3) << 3);
        const ushort_t* gA1 = A + (size_t)(rowBase + (c1 >> 2)) * K + ((c1 & 3) << 3);
        const ushort_t* gB1 = Bt + (size_t)(colBase + (c1 >> 2)) * K + ((c1 & 3) << 3);
        const int nt = K >> 5;   // K in {96,256} -> nt in {3,8}
        GEMM_PIPELINE(nt);

        // epilogue: al_s/al_d per (row, head) + bf16 h store (NCOL=256)
        int head = (colBase + wn) >> 6;
        float avs[4], avd[4];
#pragma unroll
        for (int j = 0; j < 4; j++) {
            avs[j] = a_src[head * 64 + j * 16 + lrow];
            avd[j] = a_dst[head * 64 + j * 16 + lrow];
        }
#pragma unroll
        for (int i = 0; i < 4; i++) {
#pragma unroll
            for (int r = 0; r < 4; r++) {
                float ps = 0.f, pd = 0.f;
#pragma unroll
                for (int j = 0; j < 4; j++) {
                    ps += acc[i][j][r] * avs[j];
                    pd += acc[i][j][r] * avd[j];
                }
#pragma unroll
                for (int off = 1; off < 16; off <<= 1) {
                    ps += __shfl_xor(ps, off);
                    pd += __shfl_xor(pd, off);
                }
                if (lrow == 0) {
                    int gr = rowBase + wm + i * 16 + lquad * 4 + r;
                    al_s[gr * 4 + head] = ps;
                    al_d[gr * 4 + head] = pd;
                }
            }
            int grb = rowBase + wm + i * 16 + lquad * 4;
#pragma unroll
            for (int j = 0; j < 4; j++) {
                int gc = colBase + wn + j * 16 + lrow;
#pragma unroll
                for (int r = 0; r < 4; r++)
                    Hbf[(size_t)(grb + r) * 256 + gc] = f2bf(acc[i][j][r]);
            }
        }
    } else {
        // ---------------- aux MLP GEMM path ----------------
        int id = (blockIdx.y - yMain) * 2 + blockIdx.x;   // gridDim.x == 2
        if (id >= xCnt) return;
        int bxp = id % xGX, byp = id / xGX;
        int rowBase = byp << 7;
        int colBase = bxp << 7;
        const ushort_t* gA0 = xA + (size_t)(rowBase + (c0 >> 2)) * xK + ((c0 & 3) << 3);
        const ushort_t* gB0 = xBt + (size_t)(colBase + (c0 >> 2)) * xK + ((c0 & 3) << 3);
        const ushort_t* gA1 = xA + (size_t)(rowBase + (c1 >> 2)) * xK + ((c1 & 3) << 3);
        const ushort_t* gB1 = xBt + (size_t)(colBase + (c1 >> 2)) * xK + ((c1 & 3) << 3);
        const int nt = xK >> 5;   // K in {64,512} -> nt in {2,16}
        GEMM_PIPELINE(nt);

#pragma unroll
        for (int i = 0; i < 4; i++) {
            int gr = rowBase + wm + i * 16 + lquad * 4;
#pragma unroll
            for (int j = 0; j < 4; j++) {
                int gc = colBase + wn + j * 16 + lrow;
                if (gc >= xN) continue;
                float b = xBias ? xBias[gc] : 0.f;
#pragma unroll
                for (int r = 0; r < 4; r++) {
                    float v = acc[i][j][r] + b;
                    if (xAct) v = lrelu(v, xSlope);
                    if (xOutBf)
                        ((ushort_t*)xC)[(size_t)(gr + r) * xN + gc] = f2bf(v);
                    else
                        ((float*)xC)[(size_t)(gr + r) * xN + gc] = v;
                }
            }
        }
    }
}

// ---------------- bf16 MFMA GEMM (+bias,+lrelu), register-staged (fc) ------
__global__ __launch_bounds__(256) void gemm_plain(
    const ushort_t* __restrict__ A, const ushort_t* __restrict__ Bt,
    const float* __restrict__ bias, void* __restrict__ Cout,
    int M, int N, int K, int act, float slope, int outBf) {
    __shared__ __align__(16) ushort_t As[2][128 * 32];
    __shared__ __align__(16) ushort_t Bs[2][128 * 32];
    int t = threadIdx.x;
    int wave = t >> 6, lane = t & 63;
    int wm = (wave >> 1) << 6;
    int wn = (wave & 1) << 6;
    int rowBase = blockIdx.y << 7;
    int colBase = blockIdx.x << 7;
    int lrow = lane & 15, lquad = lane >> 4;
    floatx4 acc[4][4];
#pragma unroll
    for (int i = 0; i < 4; i++)
#pragma unroll
        for (int j = 0; j < 4; j++) acc[i][j] = (floatx4){0.f, 0.f, 0.f, 0.f};

    int c0 = wave * 64 + lane;
    const ushort_t* gA0 = A + (size_t)(rowBase + (c0 >> 2)) * K + ((c0 & 3) << 3);
    const ushort_t* gB0 = Bt + (size_t)(colBase + (c0 >> 2)) * K + ((c0 & 3) << 3);
    int c1 = 256 + c0;
    const ushort_t* gA1 = A + (size_t)(rowBase + (c1 >> 2)) * K + ((c1 & 3) << 3);
    const ushort_t* gB1 = Bt + (size_t)(colBase + (c1 >> 2)) * K + ((c1 & 3) << 3);
    const int wsl0 = (wave * 64 + lane) * 8;
    const int wsl1 = (256 + wave * 64 + lane) * 8;

    const int nt = K >> 5;   // K = 256 (fc) -> 8
    GEMM_PIPELINE(nt);

#pragma unroll
    for (int i = 0; i < 4; i++) {
        int gr = rowBase + wm + i * 16 + lquad * 4;
#pragma unroll
        for (int j = 0; j < 4; j++) {
            int gc = colBase + wn + j * 16 + lrow;
            if (gc >= N) continue;
            float b = bias ? bias[gc] : 0.f;
#pragma unroll
            for (int r = 0; r < 4; r++) {
                float v = acc[i][j][r] + b;
                if (act) v = lrelu(v, slope);
                if (outBf)
                    ((ushort_t*)Cout)[(size_t)(gr + r) * N + gc] = f2bf(v);
                else
                    ((float*)Cout)[(size_t)(gr + r) * N + gc] = v;
            }
        }
    }
}

// ---------------- aggregation: TWO nodes per wave, batch-4 gather ------------
// lanes 0-31 -> node A, 32-63 -> node B; 16B/lane (8 channels, ushort8).
__global__ __launch_bounds__(256) void gat_agg(
    const ushort_t* __restrict__ h_bf, const float* __restrict__ al_s,
    const float* __restrict__ al_d, const int* __restrict__ row_ptr,
    const int* __restrict__ col, const float* __restrict__ bias,
    ushort_t* __restrict__ out_bf, int N, int act, float slope) {
    int wid = (blockIdx.x * 256 + threadIdx.x) >> 6;   // wave index
    int lane = threadIdx.x & 63;
    int half = lane >> 5;
    int lane8 = lane & 31;
    int n = wid * 2 + half;
    if (n >= N) return;
    int head = lane8 >> 3;                 // 8 lanes per head, 8 ch per lane
    int idx4 = n * 4 + head;
    float ad = al_d[idx4];
    const ushort8v* h8 = (const ushort8v*)h_bf;   // row stride 32 ushort8
    // self loop
    float p = __expf(lrelu(al_s[idx4] + ad, GAT_SLOPE));
    ushort8v hv = h8[(size_t)n * 32 + lane8];
    float s = p;
    float acc[8];
#pragma unroll
    for (int c = 0; c < 8; c++) acc[c] = p * bf2f(hv[c]);
    int beg = row_ptr[n], end = row_ptr[n + 1];
    for (int i = beg; i < end; i += 4) {
        int cnt = end - i;
        int sn0 = col[i];
        int sn1 = (cnt > 1) ? col[i + 1] : sn0;
        int sn2 = (cnt > 2) ? col[i + 2] : sn0;
        int sn3 = (cnt > 3) ? col[i + 3] : sn0;
        ushort8v h0 = h8[(size_t)sn0 * 32 + lane8];
        ushort8v h1 = h8[(size_t)sn1 * 32 + lane8];
        ushort8v h2 = h8[(size_t)sn2 * 32 + lane8];
        ushort8v h3 = h8[(size_t)sn3 * 32 + lane8];
        float a0 = al_s[sn0 * 4 + head];
        float a1 = al_s[sn1 * 4 + head];
        float a2 = al_s[sn2 * 4 + head];
        float a3 = al_s[sn3 * 4 + head];
        float p0 = __expf(lrelu(a0 + ad, GAT_SLOPE));
#pragma unroll
        for (int c = 0; c < 8; c++) acc[c] += p0 * bf2f(h0[c]);
        s += p0;
        if (cnt > 1) {
            float p1 = __expf(lrelu(a1 + ad, GAT_SLOPE));
#pragma unroll
            for (int c = 0; c < 8; c++) acc[c] += p1 * bf2f(h1[c]);
            s += p1;
        }
        if (cnt > 2) {
            float p2 = __expf(lrelu(a2 + ad, GAT_SLOPE));
#pragma unroll
            for (int c = 0; c < 8; c++) acc[c] += p2 * bf2f(h2[c]);
            s += p2;
        }
        if (cnt > 3) {
            float p3 = __expf(lrelu(a3 + ad, GAT_SLOPE));
#pragma unroll
            for (int c = 0; c < 8; c++) acc[c] += p3 * bf2f(h3[c]);
            s += p3;
        }
    }
    float rs = 1.f / s;
    const float4* b4 = (const float4*)bias;
    float4 b0 = b4[lane8 * 2];
    float4 b1 = b4[lane8 * 2 + 1];
    float bv[8] = {b0.x, b0.y, b0.z, b0.w, b1.x, b1.y, b1.z, b1.w};
    ushort8v o;
#pragma unroll
    for (int c = 0; c < 8; c++) {
        float v = acc[c] * rs + bv[c];
        if (act) v = lrelu(v, slope);
        o[c] = f2bf(v);
    }
    ((ushort8v*)out_bf)[(size_t)n * 32 + lane8] = o;
}

// ---------------------------------------------------------------------------
extern "C" void kernel_launch(void* const* d_in, const int* in_sizes, int n_in,
                              void* d_out, int out_size, void* d_ws, size_t ws_size,
                              hipStream_t stream) {
    const float* x        = (const float*)d_in[0];
    const int*   rawEdge  = (const int*)d_in[1];
    const float* rootCtx  = (const float*)d_in[2];
    const float* W[3]     = {(const float*)d_in[3], (const float*)d_in[7], (const float*)d_in[11]};
    const float* aS[3]    = {(const float*)d_in[4], (const float*)d_in[8], (const float*)d_in[12]};
    const float* aD[3]    = {(const float*)d_in[5], (const float*)d_in[9], (const float*)d_in[13]};
    const float* bb[3]    = {(const float*)d_in[6], (const float*)d_in[10], (const float*)d_in[14]};
    const float* fc_w     = (const float*)d_in[15];
    const float* fc_b     = (const float*)d_in[16];
    const float* r_w1     = (const float*)d_in[17];
    const float* r_b1     = (const float*)d_in[18];
    const float* r_w2     = (const float*)d_in[19];
    const float* r_b2     = (const float*)d_in[20];
    const float* r_w3     = (const float*)d_in[21];
    const float* r_b3     = (const float*)d_in[22];

    const int N  = in_sizes[0] / 80;      // 102400
    const int E  = in_sizes[1] / 2;       // 409600
    const int R  = in_sizes[2] / 60;      // 4096
    const int N4 = N * 4;

    float* outRot  = (float*)d_out;                  // [N, 80]
    float* outRoot = (float*)d_out + (size_t)N * 80; // [R, 60]

    // ---- carve workspace ----
    size_t off = 0;
    auto carve = [&](size_t bytes) -> void* {
        off = (off + 255) & ~(size_t)255;
        void* p = (char*)d_ws + off;
        off += bytes;
        return p;
    };
    int*      flag      = (int*)carve(4);
    int*      idx32     = (int*)carve((size_t)2 * E * 4);
    int*      counts    = (int*)carve((size_t)N * 4);
    int*      cursor    = (int*)carve((size_t)N * 4);
    int*      row_ptr   = (int*)carve((size_t)(N + 1) * 4);
    int*      incArr    = (int*)carve((size_t)N * 4);
    int*      blockSums = (int*)carve(512 * 4);
    int*      colArr    = (int*)carve((size_t)E * 4);
    float*    al_s      = (float*)carve((size_t)N4 * 4);
    float*    al_d      = (float*)carve((size_t)N4 * 4);
    ushort_t* h_bf      = (ushort_t*)carve((size_t)N * 256 * 2);
    ushort_t* agg_bf    = (ushort_t*)carve((size_t)N * 256 * 2);
    ushort_t* x_bf      = (ushort_t*)carve((size_t)N * 96 * 2);    // Kp=96
    ushort_t* rc_bf     = (ushort_t*)carve((size_t)R * 64 * 2);
    ushort_t* t1_bf     = (ushort_t*)carve((size_t)R * 512 * 2);
    ushort_t* t2_bf     = (ushort_t*)carve((size_t)R * 512 * 2);
    ushort_t* Wt0       = (ushort_t*)carve((size_t)256 * 96 * 2);  // Kp=96
    ushort_t* Wt1       = (ushort_t*)carve((size_t)256 * 256 * 2);
    ushort_t* Wt2       = (ushort_t*)carve((size_t)256 * 256 * 2);
    ushort_t* fcWt      = (ushort_t*)carve((size_t)128 * 256 * 2);
    ushort_t* rW1t      = (ushort_t*)carve((size_t)512 * 64 * 2);
    ushort_t* rWt2      = (ushort_t*)carve((size_t)512 * 512 * 2);
    ushort_t* rWt3      = (ushort_t*)carve((size_t)128 * 512 * 2);

    const int nb = (N + 255) / 256;
    dim3 blk(256);

    // ---- edge format + CSR build ----
    detect_fmt<<<1, 256, 0, stream>>>(rawEdge, 2 * E, flag);
    zero2<<<(N + 255) / 256, blk, 0, stream>>>(counts, cursor, N);
    convert_count<<<(E + 255) / 256, blk, 0, stream>>>(rawEdge, E, flag, idx32, counts);
    const int* srcArr = idx32;
    const int* dstArr = idx32 + E;
    scan_block<<<nb, 256, 0, stream>>>(counts, incArr, blockSums, N);
    scan_sums<<<1, 512, 0, stream>>>(blockSums, nb, row_ptr);
    scan_add<<<nb, 256, 0, stream>>>(incArr, blockSums, row_ptr, N);
    edge_fill<<<(E + 255) / 256, blk, 0, stream>>>(srcArr, dstArr, E, row_ptr, cursor, colArr);

    // ---- weight conversions (merged) ----
    {
        WConvArr wa;
        auto mk = [&](int i, const float* in, ushort_t* out, int Kp, int Kr, int Nn, int Npad,
                      int blkOff) {
            wa.e[i] = WConv{in, out, Kp, Kr, Nn, Npad, blkOff};
        };
        int boff = 0;
        auto nblk = [](int Npad, int Kp) { return (Npad * Kp + 255) / 256; };
        mk(0, W[0], Wt0, 96, 80, 256, 256, boff);   boff += nblk(256, 96);
        mk(1, W[1], Wt1, 256, 256, 256, 256, boff); boff += nblk(256, 256);
        mk(2, W[2], Wt2, 256, 256, 256, 256, boff); boff += nblk(256, 256);
        mk(3, fc_w, fcWt, 256, 256, 80, 128, boff); boff += nblk(128, 256);
        mk(4, r_w1, rW1t, 64, 60, 512, 512, boff);  boff += nblk(512, 64);
        mk(5, r_w2, rWt2, 512, 512, 512, 512, boff); boff += nblk(512, 512);
        mk(6, r_w3, rWt3, 512, 512, 60, 128, boff);  boff += nblk(128, 512);
        wa.n = 7;
        convert_w_multi<<<boff, blk, 0, stream>>>(wa);
    }
    convert_padrow<<<(N * 96 + 255) / 256, blk, 0, stream>>>(x, x_bf, N, 80, 96);
    convert_padrow<<<(R * 64 + 255) / 256, blk, 0, stream>>>(rootCtx, rc_bf, R, 60, 64);

    // ---- GAT layers with fused MLP-chain aux blocks ----
    const int aggBlocks = (N / 2 + 3) / 4;   // 2 nodes/wave, 4 waves/block
    const int yMain = N / 128;               // 800
    const ushort_t* curA = x_bf;
    int curK = 96;
    const int mlpGY = R / 128;               // 32
    for (int l = 0; l < 3; l++) {
        // aux GEMM for this launch: MLP layer l
        const ushort_t* xA  = (l == 0) ? rc_bf : (l == 1 ? t1_bf : t2_bf);
        const ushort_t* xBt = (l == 0) ? rW1t : (l == 1 ? rWt2 : rWt3);
        const float*    xB  = (l == 0) ? r_b1 : (l == 1 ? r_b2 : r_b3);
        void*           xC  = (l == 0) ? (void*)t1_bf : (l == 1 ? (void*)t2_bf : (void*)outRoot);
        int xN   = (l == 2) ? 60 : 512;
        int xK   = (l == 0) ? 64 : 512;
        int xGX  = (l == 2) ? 1 : 4;
        int xCnt = xGX * mlpGY;              // 128,128,32
        int xAct = (l == 2) ? 0 : 1;
        int xOutBf = (l == 2) ? 0 : 1;
        int extraY = (xCnt + 1) / 2;         // gridDim.x = 2
        dim3 g1(2, yMain + extraY);
        gemm_gat<<<g1, blk, 0, stream>>>(curA, l == 0 ? Wt0 : (l == 1 ? Wt1 : Wt2),
                                         aS[l], aD[l], h_bf, al_s, al_d,
                                         curK, yMain,
                                         xA, xBt, xB, xC,
                                         xN, xK, xGX, xCnt, xAct, ACT_SLOPE, xOutBf);
        int act = (l < 2) ? 1 : 0;
        gat_agg<<<aggBlocks, blk, 0, stream>>>(h_bf, al_s, al_d, row_ptr,
                                               colArr, bb[l], agg_bf, N,
                                               act, ACT_SLOPE);
        curA = agg_bf;
        curK = 256;
    }

    // ---- rot = h @ fc_w + fc_b ----
    {
        dim3 g(1, N / 128);
        gemm_plain<<<g, blk, 0, stream>>>(agg_bf, fcWt, fc_b, outRot, N, 80, 256,
                                          0, 0.f, 0);
    }
}

// Round 14
// 469.393 us; speedup vs baseline: 1.1800x; 1.0253x over previous
//
#include <hip/hip_runtime.h>
#include <hip/hip_bf16.h>

// ---------------------------------------------------------------------------
// GAT x3 + fc + MLP. R24 = R23 resubmitted verbatim (round 13 died on
// container acquire; kernel never measured). R22 (481.3us) fused the MLP
// chain into the gemm_gat launches as tail blocks; counters showed the aux
// blocks (nt=16, 2x GAT block duration) dispatched LAST -> ~20us half-idle
// tail (gemm_gat 47 -> 70us). R23/R24 moves aux blocks to the FRONT of the
// grid (lowest blockIdx.y, dispatched first) to overlap them with the GAT
// wave. All other code identical to R22.
// ---------------------------------------------------------------------------

#define GAT_SLOPE 0.2f
#define ACT_SLOPE 0.01f

typedef unsigned short ushort_t;
typedef __attribute__((ext_vector_type(8))) short bf16x8;
typedef __attribute__((ext_vector_type(8))) unsigned short ushort8v;
typedef __attribute__((ext_vector_type(4))) float floatx4;

__device__ __forceinline__ float lrelu(float x, float s) {
    return fmaxf(x, s * x);   // valid for 0<s<1
}

__device__ __forceinline__ ushort_t f2bf(float f) {
    union { float f; unsigned u; } x; x.f = f;
    unsigned r = x.u + 0x7FFF + ((x.u >> 16) & 1);   // round-nearest-even
    return (ushort_t)(r >> 16);
}

__device__ __forceinline__ float bf2f(ushort_t u) {
    union { unsigned u; float f; } x; x.u = ((unsigned)u) << 16;
    return x.f;
}

// ---------------- edge-index format probe ----------------
__global__ void detect_fmt(const int* __restrict__ raw, int nwords, int* flag) {
    __shared__ int nz;
    if (threadIdx.x == 0) nz = 0;
    __syncthreads();
    int lim = nwords < 4096 ? nwords : 4096;
    for (int i = threadIdx.x * 2 + 1; i < lim; i += 512)
        if (raw[i] != 0) atomicAdd(&nz, 1);
    __syncthreads();
    if (threadIdx.x == 0) *flag = (nz == 0) ? 1 : 0;   // 1 => int64 storage
}

__global__ void zero2(int* __restrict__ a, int* __restrict__ b, int n) {
    int i = blockIdx.x * blockDim.x + threadIdx.x;
    if (i < n) { a[i] = 0; b[i] = 0; }
}

__global__ void convert_count(const int* __restrict__ raw, int E,
                              const int* __restrict__ flag,
                              int* __restrict__ idx32, int* __restrict__ counts) {
    int i = blockIdx.x * blockDim.x + threadIdx.x;
    if (i >= E) return;
    int f = *flag;
    int s = f ? raw[2 * i] : raw[i];
    int d = f ? raw[2 * (E + i)] : raw[E + i];
    idx32[i] = s;
    idx32[E + i] = d;
    atomicAdd(&counts[d], 1);
}

__global__ void scan_block(const int* __restrict__ counts, int* __restrict__ inc,
                           int* __restrict__ blockSums, int N) {
    __shared__ int sh[256];
    int i = blockIdx.x * 256 + threadIdx.x;
    int v = (i < N) ? counts[i] : 0;
    sh[threadIdx.x] = v;
    __syncthreads();
    for (int off = 1; off < 256; off <<= 1) {
        int t = (threadIdx.x >= off) ? sh[threadIdx.x - off] : 0;
        __syncthreads();
        sh[threadIdx.x] += t;
        __syncthreads();
    }
    if (i < N) inc[i] = sh[threadIdx.x];
    if (threadIdx.x == 255) blockSums[blockIdx.x] = sh[255];
}

__global__ void scan_sums(int* __restrict__ blockSums, int nb, int* __restrict__ row_ptr) {
    __shared__ int sh[512];
    int v = ((int)threadIdx.x < nb) ? blockSums[threadIdx.x] : 0;
    sh[threadIdx.x] = v;
    __syncthreads();
    for (int off = 1; off < 512; off <<= 1) {
        int t = (threadIdx.x >= off) ? sh[threadIdx.x - off] : 0;
        __syncthreads();
        sh[threadIdx.x] += t;
        __syncthreads();
    }
    if ((int)threadIdx.x < nb) blockSums[threadIdx.x] = sh[threadIdx.x];
    if (threadIdx.x == 0) row_ptr[0] = 0;
}

__global__ void scan_add(const int* __restrict__ inc, const int* __restrict__ blockSums,
                         int* __restrict__ row_ptr, int N) {
    int i = blockIdx.x * 256 + threadIdx.x;
    if (i < N) row_ptr[i + 1] = inc[i] + (blockIdx.x > 0 ? blockSums[blockIdx.x - 1] : 0);
}

__global__ void edge_fill(const int* __restrict__ src, const int* __restrict__ dst, int E,
                          const int* __restrict__ row_ptr, int* __restrict__ cursor,
                          int* __restrict__ col) {
    int i = blockIdx.x * blockDim.x + threadIdx.x;
    if (i < E) {
        int d = dst[i];
        int pos = row_ptr[d] + atomicAdd(&cursor[d], 1);
        col[pos] = src[i];
    }
}

// ---------------- conversions ----------------
__global__ void convert_padrow(const float* __restrict__ in, ushort_t* __restrict__ out,
                               int M, int Kr, int Kp) {
    int i = blockIdx.x * blockDim.x + threadIdx.x;
    if (i >= M * Kp) return;
    int r = i / Kp, c = i - r * Kp;
    out[i] = f2bf((c < Kr) ? in[(size_t)r * Kr + c] : 0.f);
}

struct WConv { const float* in; ushort_t* out; int Kp, Kr, N, Npad, blkOff; };
struct WConvArr { WConv e[7]; int n; };

__global__ void convert_w_multi(WConvArr a) {
    int b = blockIdx.x;
    int ei = 0;
    for (int k = 1; k < a.n; k++)
        if (b >= a.e[k].blkOff) ei = k;
    WConv w = a.e[ei];
    int i = (b - w.blkOff) * 256 + threadIdx.x;
    if (i >= w.Npad * w.Kp) return;
    int n = i / w.Kp, k = i - n * w.Kp;
    float v = (n < w.N && k < w.Kr) ? w.in[(size_t)k * w.N + n] : 0.f;
    w.out[i] = f2bf(v);
}

// ---- R19 reg-staged pipeline macros (proven best loop structure) ----------
#define LOADR(tt)                                     \
    do {                                              \
        int k0_ = (tt) << 5;                          \
        rA0 = *(const ushort8v*)(gA0 + k0_);          \
        rA1 = *(const ushort8v*)(gA1 + k0_);          \
        rB0 = *(const ushort8v*)(gB0 + k0_);          \
        rB1 = *(const ushort8v*)(gB1 + k0_);          \
    } while (0)

#define WRITER(b)                                     \
    do {                                              \
        *(ushort8v*)(&As[b][wsl0]) = rA0;             \
        *(ushort8v*)(&As[b][wsl1]) = rA1;             \
        *(ushort8v*)(&Bs[b][wsl0]) = rB0;             \
        *(ushort8v*)(&Bs[b][wsl1]) = rB1;             \
    } while (0)

#define GEMM_PIPELINE(NT)                                                        \
    ushort8v rA0, rA1, rB0, rB1;                                                 \
    LOADR(0);                                                                    \
    WRITER(0);                                                                   \
    LOADR(1);                                                                    \
    asm volatile("s_waitcnt lgkmcnt(0)" ::: "memory");                           \
    __builtin_amdgcn_s_barrier();                                                \
    for (int kt = 0; kt < (NT); ++kt) {                                          \
        int b = kt & 1;                                                          \
        if (kt + 1 < (NT)) WRITER(b ^ 1);                                        \
        if (kt + 2 < (NT)) LOADR(kt + 2);                                        \
        bf16x8 af[4], bfv[4];                                                    \
        _Pragma("unroll")                                                        \
        for (int i = 0; i < 4; i++)                                              \
            af[i] = *(const bf16x8*)(&As[b][(wm + i * 16 + lrow) * 32            \
                                            + lquad * 8]);                       \
        _Pragma("unroll")                                                        \
        for (int j = 0; j < 4; j++)                                              \
            bfv[j] = *(const bf16x8*)(&Bs[b][(wn + j * 16 + lrow) * 32           \
                                             + lquad * 8]);                      \
        _Pragma("unroll")                                                        \
        for (int i = 0; i < 4; i++)                                              \
            _Pragma("unroll")                                                    \
            for (int j = 0; j < 4; j++)                                          \
                acc[i][j] = __builtin_amdgcn_mfma_f32_16x16x32_bf16(             \
                    af[i], bfv[j], acc[i][j], 0, 0, 0);                          \
        asm volatile("s_waitcnt lgkmcnt(0)" ::: "memory");                       \
        __builtin_amdgcn_s_barrier();                                            \
    }

// ---------------- unified GAT GEMM + auxiliary MLP GEMM (front blocks) -----
// blocks with by < auxY: one MLP-chain GEMM layer (dispatched FIRST, overlaps
// the GAT wave). blocks with by >= auxY: GAT GEMM (h = A@W + al epilogue).
__global__ __launch_bounds__(256) void gemm_gat(
    const ushort_t* __restrict__ A, const ushort_t* __restrict__ Bt,
    const float* __restrict__ a_src, const float* __restrict__ a_dst,
    ushort_t* __restrict__ Hbf, float* __restrict__ al_s, float* __restrict__ al_d,
    int K, int auxY,
    const ushort_t* __restrict__ xA, const ushort_t* __restrict__ xBt,
    const float* __restrict__ xBias, void* __restrict__ xC,
    int xN, int xK, int xGX, int xCnt, int xAct, float xSlope, int xOutBf) {
    __shared__ __align__(16) ushort_t As[2][128 * 32];
    __shared__ __align__(16) ushort_t Bs[2][128 * 32];
    int t = threadIdx.x;
    int wave = t >> 6, lane = t & 63;
    int wm = (wave >> 1) << 6;
    int wn = (wave & 1) << 6;
    int lrow = lane & 15, lquad = lane >> 4;
    const int wsl0 = (wave * 64 + lane) * 8;
    const int wsl1 = (256 + wave * 64 + lane) * 8;
    int c0 = wave * 64 + lane;
    int c1 = 256 + c0;

    floatx4 acc[4][4];
#pragma unroll
    for (int i = 0; i < 4; i++)
#pragma unroll
        for (int j = 0; j < 4; j++) acc[i][j] = (floatx4){0.f, 0.f, 0.f, 0.f};

    if ((int)blockIdx.y >= auxY) {
        // ---------------- GAT path ----------------
        int rowBase = (blockIdx.y - auxY) << 7;
        int colBase = blockIdx.x << 7;
        const ushort_t* gA0 = A + (size_t)(rowBase + (c0 >> 2)) * K + ((c0 & 3) << 3);
        const ushort_t* gB0 = Bt + (size_t)(colBase + (c0 >> 2)) * K + ((c0 & 3) << 3);
        const ushort_t* gA1 = A + (size_t)(rowBase + (c1 >> 2)) * K + ((c1 & 3) << 3);
        const ushort_t* gB1 = Bt + (size_t)(colBase + (c1 >> 2)) * K + ((c1 & 3) << 3);
        const int nt = K >> 5;   // K in {96,256} -> nt in {3,8}
        GEMM_PIPELINE(nt);

        // epilogue: al_s/al_d per (row, head) + bf16 h store (NCOL=256)
        int head = (colBase + wn) >> 6;
        float avs[4], avd[4];
#pragma unroll
        for (int j = 0; j < 4; j++) {
            avs[j] = a_src[head * 64 + j * 16 + lrow];
            avd[j] = a_dst[head * 64 + j * 16 + lrow];
        }
#pragma unroll
        for (int i = 0; i < 4; i++) {
#pragma unroll
            for (int r = 0; r < 4; r++) {
                float ps = 0.f, pd = 0.f;
#pragma unroll
                for (int j = 0; j < 4; j++) {
                    ps += acc[i][j][r] * avs[j];
                    pd += acc[i][j][r] * avd[j];
                }
#pragma unroll
                for (int off = 1; off < 16; off <<= 1) {
                    ps += __shfl_xor(ps, off);
                    pd += __shfl_xor(pd, off);
                }
                if (lrow == 0) {
                    int gr = rowBase + wm + i * 16 + lquad * 4 + r;
                    al_s[gr * 4 + head] = ps;
                    al_d[gr * 4 + head] = pd;
                }
            }
            int grb = rowBase + wm + i * 16 + lquad * 4;
#pragma unroll
            for (int j = 0; j < 4; j++) {
                int gc = colBase + wn + j * 16 + lrow;
#pragma unroll
                for (int r = 0; r < 4; r++)
                    Hbf[(size_t)(grb + r) * 256 + gc] = f2bf(acc[i][j][r]);
            }
        }
    } else {
        // ---------------- aux MLP GEMM path (front) ----------------
        int id = blockIdx.y * 2 + blockIdx.x;   // gridDim.x == 2
        if (id >= xCnt) return;
        int bxp = id % xGX, byp = id / xGX;
        int rowBase = byp << 7;
        int colBase = bxp << 7;
        const ushort_t* gA0 = xA + (size_t)(rowBase + (c0 >> 2)) * xK + ((c0 & 3) << 3);
        const ushort_t* gB0 = xBt + (size_t)(colBase + (c0 >> 2)) * xK + ((c0 & 3) << 3);
        const ushort_t* gA1 = xA + (size_t)(rowBase + (c1 >> 2)) * xK + ((c1 & 3) << 3);
        const ushort_t* gB1 = xBt + (size_t)(colBase + (c1 >> 2)) * xK + ((c1 & 3) << 3);
        const int nt = xK >> 5;   // K in {64,512} -> nt in {2,16}
        GEMM_PIPELINE(nt);

#pragma unroll
        for (int i = 0; i < 4; i++) {
            int gr = rowBase + wm + i * 16 + lquad * 4;
#pragma unroll
            for (int j = 0; j < 4; j++) {
                int gc = colBase + wn + j * 16 + lrow;
                if (gc >= xN) continue;
                float b = xBias ? xBias[gc] : 0.f;
#pragma unroll
                for (int r = 0; r < 4; r++) {
                    float v = acc[i][j][r] + b;
                    if (xAct) v = lrelu(v, xSlope);
                    if (xOutBf)
                        ((ushort_t*)xC)[(size_t)(gr + r) * xN + gc] = f2bf(v);
                    else
                        ((float*)xC)[(size_t)(gr + r) * xN + gc] = v;
                }
            }
        }
    }
}

// ---------------- bf16 MFMA GEMM (+bias,+lrelu), register-staged (fc) ------
__global__ __launch_bounds__(256) void gemm_plain(
    const ushort_t* __restrict__ A, const ushort_t* __restrict__ Bt,
    const float* __restrict__ bias, void* __restrict__ Cout,
    int M, int N, int K, int act, float slope, int outBf) {
    __shared__ __align__(16) ushort_t As[2][128 * 32];
    __shared__ __align__(16) ushort_t Bs[2][128 * 32];
    int t = threadIdx.x;
    int wave = t >> 6, lane = t & 63;
    int wm = (wave >> 1) << 6;
    int wn = (wave & 1) << 6;
    int rowBase = blockIdx.y << 7;
    int colBase = blockIdx.x << 7;
    int lrow = lane & 15, lquad = lane >> 4;
    floatx4 acc[4][4];
#pragma unroll
    for (int i = 0; i < 4; i++)
#pragma unroll
        for (int j = 0; j < 4; j++) acc[i][j] = (floatx4){0.f, 0.f, 0.f, 0.f};

    int c0 = wave * 64 + lane;
    const ushort_t* gA0 = A + (size_t)(rowBase + (c0 >> 2)) * K + ((c0 & 3) << 3);
    const ushort_t* gB0 = Bt + (size_t)(colBase + (c0 >> 2)) * K + ((c0 & 3) << 3);
    int c1 = 256 + c0;
    const ushort_t* gA1 = A + (size_t)(rowBase + (c1 >> 2)) * K + ((c1 & 3) << 3);
    const ushort_t* gB1 = Bt + (size_t)(colBase + (c1 >> 2)) * K + ((c1 & 3) << 3);
    const int wsl0 = (wave * 64 + lane) * 8;
    const int wsl1 = (256 + wave * 64 + lane) * 8;

    const int nt = K >> 5;   // K = 256 (fc) -> 8
    GEMM_PIPELINE(nt);

#pragma unroll
    for (int i = 0; i < 4; i++) {
        int gr = rowBase + wm + i * 16 + lquad * 4;
#pragma unroll
        for (int j = 0; j < 4; j++) {
            int gc = colBase + wn + j * 16 + lrow;
            if (gc >= N) continue;
            float b = bias ? bias[gc] : 0.f;
#pragma unroll
            for (int r = 0; r < 4; r++) {
                float v = acc[i][j][r] + b;
                if (act) v = lrelu(v, slope);
                if (outBf)
                    ((ushort_t*)Cout)[(size_t)(gr + r) * N + gc] = f2bf(v);
                else
                    ((float*)Cout)[(size_t)(gr + r) * N + gc] = v;
            }
        }
    }
}

// ---------------- aggregation: TWO nodes per wave, batch-4 gather ------------
// lanes 0-31 -> node A, 32-63 -> node B; 16B/lane (8 channels, ushort8).
__global__ __launch_bounds__(256) void gat_agg(
    const ushort_t* __restrict__ h_bf, const float* __restrict__ al_s,
    const float* __restrict__ al_d, const int* __restrict__ row_ptr,
    const int* __restrict__ col, const float* __restrict__ bias,
    ushort_t* __restrict__ out_bf, int N, int act, float slope) {
    int wid = (blockIdx.x * 256 + threadIdx.x) >> 6;   // wave index
    int lane = threadIdx.x & 63;
    int half = lane >> 5;
    int lane8 = lane & 31;
    int n = wid * 2 + half;
    if (n >= N) return;
    int head = lane8 >> 3;                 // 8 lanes per head, 8 ch per lane
    int idx4 = n * 4 + head;
    float ad = al_d[idx4];
    const ushort8v* h8 = (const ushort8v*)h_bf;   // row stride 32 ushort8
    // self loop
    float p = __expf(lrelu(al_s[idx4] + ad, GAT_SLOPE));
    ushort8v hv = h8[(size_t)n * 32 + lane8];
    float s = p;
    float acc[8];
#pragma unroll
    for (int c = 0; c < 8; c++) acc[c] = p * bf2f(hv[c]);
    int beg = row_ptr[n], end = row_ptr[n + 1];
    for (int i = beg; i < end; i += 4) {
        int cnt = end - i;
        int sn0 = col[i];
        int sn1 = (cnt > 1) ? col[i + 1] : sn0;
        int sn2 = (cnt > 2) ? col[i + 2] : sn0;
        int sn3 = (cnt > 3) ? col[i + 3] : sn0;
        ushort8v h0 = h8[(size_t)sn0 * 32 + lane8];
        ushort8v h1 = h8[(size_t)sn1 * 32 + lane8];
        ushort8v h2 = h8[(size_t)sn2 * 32 + lane8];
        ushort8v h3 = h8[(size_t)sn3 * 32 + lane8];
        float a0 = al_s[sn0 * 4 + head];
        float a1 = al_s[sn1 * 4 + head];
        float a2 = al_s[sn2 * 4 + head];
        float a3 = al_s[sn3 * 4 + head];
        float p0 = __expf(lrelu(a0 + ad, GAT_SLOPE));
#pragma unroll
        for (int c = 0; c < 8; c++) acc[c] += p0 * bf2f(h0[c]);
        s += p0;
        if (cnt > 1) {
            float p1 = __expf(lrelu(a1 + ad, GAT_SLOPE));
#pragma unroll
            for (int c = 0; c < 8; c++) acc[c] += p1 * bf2f(h1[c]);
            s += p1;
        }
        if (cnt > 2) {
            float p2 = __expf(lrelu(a2 + ad, GAT_SLOPE));
#pragma unroll
            for (int c = 0; c < 8; c++) acc[c] += p2 * bf2f(h2[c]);
            s += p2;
        }
        if (cnt > 3) {
            float p3 = __expf(lrelu(a3 + ad, GAT_SLOPE));
#pragma unroll
            for (int c = 0; c < 8; c++) acc[c] += p3 * bf2f(h3[c]);
            s += p3;
        }
    }
    float rs = 1.f / s;
    const float4* b4 = (const float4*)bias;
    float4 b0 = b4[lane8 * 2];
    float4 b1 = b4[lane8 * 2 + 1];
    float bv[8] = {b0.x, b0.y, b0.z, b0.w, b1.x, b1.y, b1.z, b1.w};
    ushort8v o;
#pragma unroll
    for (int c = 0; c < 8; c++) {
        float v = acc[c] * rs + bv[c];
        if (act) v = lrelu(v, slope);
        o[c] = f2bf(v);
    }
    ((ushort8v*)out_bf)[(size_t)n * 32 + lane8] = o;
}

// ---------------------------------------------------------------------------
extern "C" void kernel_launch(void* const* d_in, const int* in_sizes, int n_in,
                              void* d_out, int out_size, void* d_ws, size_t ws_size,
                              hipStream_t stream) {
    const float* x        = (const float*)d_in[0];
    const int*   rawEdge  = (const int*)d_in[1];
    const float* rootCtx  = (const float*)d_in[2];
    const float* W[3]     = {(const float*)d_in[3], (const float*)d_in[7], (const float*)d_in[11]};
    const float* aS[3]    = {(const float*)d_in[4], (const float*)d_in[8], (const float*)d_in[12]};
    const float* aD[3]    = {(const float*)d_in[5], (const float*)d_in[9], (const float*)d_in[13]};
    const float* bb[3]    = {(const float*)d_in[6], (const float*)d_in[10], (const float*)d_in[14]};
    const float* fc_w     = (const float*)d_in[15];
    const float* fc_b     = (const float*)d_in[16];
    const float* r_w1     = (const float*)d_in[17];
    const float* r_b1     = (const float*)d_in[18];
    const float* r_w2     = (const float*)d_in[19];
    const float* r_b2     = (const float*)d_in[20];
    const float* r_w3     = (const float*)d_in[21];
    const float* r_b3     = (const float*)d_in[22];

    const int N  = in_sizes[0] / 80;      // 102400
    const int E  = in_sizes[1] / 2;       // 409600
    const int R  = in_sizes[2] / 60;      // 4096
    const int N4 = N * 4;

    float* outRot  = (float*)d_out;                  // [N, 80]
    float* outRoot = (float*)d_out + (size_t)N * 80; // [R, 60]

    // ---- carve workspace ----
    size_t off = 0;
    auto carve = [&](size_t bytes) -> void* {
        off = (off + 255) & ~(size_t)255;
        void* p = (char*)d_ws + off;
        off += bytes;
        return p;
    };
    int*      flag      = (int*)carve(4);
    int*      idx32     = (int*)carve((size_t)2 * E * 4);
    int*      counts    = (int*)carve((size_t)N * 4);
    int*      cursor    = (int*)carve((size_t)N * 4);
    int*      row_ptr   = (int*)carve((size_t)(N + 1) * 4);
    int*      incArr    = (int*)carve((size_t)N * 4);
    int*      blockSums = (int*)carve(512 * 4);
    int*      colArr    = (int*)carve((size_t)E * 4);
    float*    al_s      = (float*)carve((size_t)N4 * 4);
    float*    al_d      = (float*)carve((size_t)N4 * 4);
    ushort_t* h_bf      = (ushort_t*)carve((size_t)N * 256 * 2);
    ushort_t* agg_bf    = (ushort_t*)carve((size_t)N * 256 * 2);
    ushort_t* x_bf      = (ushort_t*)carve((size_t)N * 96 * 2);    // Kp=96
    ushort_t* rc_bf     = (ushort_t*)carve((size_t)R * 64 * 2);
    ushort_t* t1_bf     = (ushort_t*)carve((size_t)R * 512 * 2);
    ushort_t* t2_bf     = (ushort_t*)carve((size_t)R * 512 * 2);
    ushort_t* Wt0       = (ushort_t*)carve((size_t)256 * 96 * 2);  // Kp=96
    ushort_t* Wt1       = (ushort_t*)carve((size_t)256 * 256 * 2);
    ushort_t* Wt2       = (ushort_t*)carve((size_t)256 * 256 * 2);
    ushort_t* fcWt      = (ushort_t*)carve((size_t)128 * 256 * 2);
    ushort_t* rW1t      = (ushort_t*)carve((size_t)512 * 64 * 2);
    ushort_t* rWt2      = (ushort_t*)carve((size_t)512 * 512 * 2);
    ushort_t* rWt3      = (ushort_t*)carve((size_t)128 * 512 * 2);

    const int nb = (N + 255) / 256;
    dim3 blk(256);

    // ---- edge format + CSR build ----
    detect_fmt<<<1, 256, 0, stream>>>(rawEdge, 2 * E, flag);
    zero2<<<(N + 255) / 256, blk, 0, stream>>>(counts, cursor, N);
    convert_count<<<(E + 255) / 256, blk, 0, stream>>>(rawEdge, E, flag, idx32, counts);
    const int* srcArr = idx32;
    const int* dstArr = idx32 + E;
    scan_block<<<nb, 256, 0, stream>>>(counts, incArr, blockSums, N);
    scan_sums<<<1, 512, 0, stream>>>(blockSums, nb, row_ptr);
    scan_add<<<nb, 256, 0, stream>>>(incArr, blockSums, row_ptr, N);
    edge_fill<<<(E + 255) / 256, blk, 0, stream>>>(srcArr, dstArr, E, row_ptr, cursor, colArr);

    // ---- weight conversions (merged) ----
    {
        WConvArr wa;
        auto mk = [&](int i, const float* in, ushort_t* out, int Kp, int Kr, int Nn, int Npad,
                      int blkOff) {
            wa.e[i] = WConv{in, out, Kp, Kr, Nn, Npad, blkOff};
        };
        int boff = 0;
        auto nblk = [](int Npad, int Kp) { return (Npad * Kp + 255) / 256; };
        mk(0, W[0], Wt0, 96, 80, 256, 256, boff);   boff += nblk(256, 96);
        mk(1, W[1], Wt1, 256, 256, 256, 256, boff); boff += nblk(256, 256);
        mk(2, W[2], Wt2, 256, 256, 256, 256, boff); boff += nblk(256, 256);
        mk(3, fc_w, fcWt, 256, 256, 80, 128, boff); boff += nblk(128, 256);
        mk(4, r_w1, rW1t, 64, 60, 512, 512, boff);  boff += nblk(512, 64);
        mk(5, r_w2, rWt2, 512, 512, 512, 512, boff); boff += nblk(512, 512);
        mk(6, r_w3, rWt3, 512, 512, 60, 128, boff);  boff += nblk(128, 512);
        wa.n = 7;
        convert_w_multi<<<boff, blk, 0, stream>>>(wa);
    }
    convert_padrow<<<(N * 96 + 255) / 256, blk, 0, stream>>>(x, x_bf, N, 80, 96);
    convert_padrow<<<(R * 64 + 255) / 256, blk, 0, stream>>>(rootCtx, rc_bf, R, 60, 64);

    // ---- GAT layers with fused MLP-chain aux blocks (front-placed) ----
    const int aggBlocks = (N / 2 + 3) / 4;   // 2 nodes/wave, 4 waves/block
    const int yMain = N / 128;               // 800
    const ushort_t* curA = x_bf;
    int curK = 96;
    const int mlpGY = R / 128;               // 32
    for (int l = 0; l < 3; l++) {
        // aux GEMM for this launch: MLP layer l
        const ushort_t* xA  = (l == 0) ? rc_bf : (l == 1 ? t1_bf : t2_bf);
        const ushort_t* xBt = (l == 0) ? rW1t : (l == 1 ? rWt2 : rWt3);
        const float*    xB  = (l == 0) ? r_b1 : (l == 1 ? r_b2 : r_b3);
        void*           xC  = (l == 0) ? (void*)t1_bf : (l == 1 ? (void*)t2_bf : (void*)outRoot);
        int xN   = (l == 2) ? 60 : 512;
        int xK   = (l == 0) ? 64 : 512;
        int xGX  = (l == 2) ? 1 : 4;
        int xCnt = xGX * mlpGY;              // 128,128,32
        int xAct = (l == 2) ? 0 : 1;
        int xOutBf = (l == 2) ? 0 : 1;
        int auxY = (xCnt + 1) / 2;           // gridDim.x = 2
        dim3 g1(2, yMain + auxY);
        gemm_gat<<<g1, blk, 0, stream>>>(curA, l == 0 ? Wt0 : (l == 1 ? Wt1 : Wt2),
                                         aS[l], aD[l], h_bf, al_s, al_d,
                                         curK, auxY,
                                         xA, xBt, xB, xC,
                                         xN, xK, xGX, xCnt, xAct, ACT_SLOPE, xOutBf);
        int act = (l < 2) ? 1 : 0;
        gat_agg<<<aggBlocks, blk, 0, stream>>>(h_bf, al_s, al_d, row_ptr,
                                               colArr, bb[l], agg_bf, N,
                                               act, ACT_SLOPE);
        curA = agg_bf;
        curK = 256;
    }

    // ---- rot = h @ fc_w + fc_b ----
    {
        dim3 g(1, N / 128);
        gemm_plain<<<g, blk, 0, stream>>>(agg_bf, fcWt, fc_b, outRot, N, 80, 256,
                                          0, 0.f, 0);
    }
}